// Round 1
// baseline (1030.702 us; speedup 1.0000x reference)
//
#include <hip/hip_runtime.h>
#include <math.h>

#define NN 100000
#define NE 1600000
#define CH 128
#define TOTE (NE + NN)
#define EPSV 1e-5f
#define NB 98  // ceil(NN/1024)

__device__ __forceinline__ float lrelu(float v, float s) { return v < 0.f ? v * s : v; }

// ---------------- CSR build ----------------
__global__ void k_init(int* __restrict__ deg, int* __restrict__ cursor, float* __restrict__ stats) {
    int i = blockIdx.x * 256 + threadIdx.x;
    if (i < NN) { deg[i] = 1; cursor[i] = 0; }   // deg=1 accounts for the self-loop
    if (i < 4096) stats[i] = 0.f;                 // both stages' stat banks
}

__global__ void k_count(const int* __restrict__ edges, int* __restrict__ deg) {
    int i = blockIdx.x * 256 + threadIdx.x;
    if (i < NE) atomicAdd(&deg[edges[NE + i]], 1);
}

__global__ void k_scan1(const int* __restrict__ deg, int* __restrict__ bsum, float* __restrict__ dinv) {
    __shared__ int red[256];
    int t = threadIdx.x;
    int base = blockIdx.x * 1024 + t * 4;
    int s = 0;
#pragma unroll
    for (int j = 0; j < 4; j++) {
        int i = base + j;
        if (i < NN) { int d = deg[i]; s += d; dinv[i] = rsqrtf((float)d); }
    }
    red[t] = s; __syncthreads();
    for (int off = 128; off > 0; off >>= 1) { if (t < off) red[t] += red[t + off]; __syncthreads(); }
    if (t == 0) bsum[blockIdx.x] = red[0];
}

__global__ void k_scan2(const int* __restrict__ bsum, int* __restrict__ boff) {
    if (threadIdx.x == 0) {
        int acc = 0;
        for (int b = 0; b < NB; b++) { boff[b] = acc; acc += bsum[b]; }
    }
}

__global__ void k_scan3(const int* __restrict__ deg, const int* __restrict__ boff, int* __restrict__ rowptr) {
    __shared__ int sc[256];
    int t = threadIdx.x;
    int base = blockIdx.x * 1024 + t * 4;
    int d[4];
#pragma unroll
    for (int j = 0; j < 4; j++) { int i = base + j; d[j] = (i < NN) ? deg[i] : 0; }
    int local = d[0] + d[1] + d[2] + d[3];
    sc[t] = local; __syncthreads();
    for (int off = 1; off < 256; off <<= 1) {
        int v = (t >= off) ? sc[t - off] : 0;
        __syncthreads();
        sc[t] += v;
        __syncthreads();
    }
    int run = sc[t] - local + boff[blockIdx.x];
#pragma unroll
    for (int j = 0; j < 4; j++) {
        int i = base + j;
        if (i < NN) { rowptr[i] = run; run += d[j]; }
    }
    if (blockIdx.x == 0 && t == 0) rowptr[NN] = TOTE;
}

__global__ void k_fill(const int* __restrict__ edges, const int* __restrict__ rowptr,
                       int* __restrict__ cursor, int* __restrict__ csr) {
    int i = blockIdx.x * 256 + threadIdx.x;
    if (i < NE) {
        int s = edges[i], d = edges[NE + i];
        int pos = atomicAdd(&cursor[d], 1);
        csr[rowptr[d] + pos] = s;
    } else if (i < TOTE) {
        int v = i - NE;
        int pos = atomicAdd(&cursor[v], 1);
        csr[rowptr[v] + pos] = v;   // self-loop
    }
}

// ---------------- GEMM 1: H = X @ W1 ----------------
// W (64KB) in LDS; 4 waves/block, each wave owns 4 rows; lane l owns output cols {2l,2l+1}.
__launch_bounds__(256, 2)
__global__ void k_gemm1(const float* __restrict__ X, const float* __restrict__ W, float* __restrict__ H) {
    __shared__ float Wl[CH * CH];
    int t = threadIdx.x;
    for (int i = t * 4; i < CH * CH; i += 1024) *(float4*)&Wl[i] = *(const float4*)&W[i];
    __syncthreads();
    int wave = t >> 6, lane = t & 63;
    for (int row0 = blockIdx.x * 16 + wave * 4; row0 < NN; row0 += gridDim.x * 16) {
        int nr = NN - row0; if (nr > 4) nr = 4;
        float2 xr0 = {0.f, 0.f}, xr1 = {0.f, 0.f}, xr2 = {0.f, 0.f}, xr3 = {0.f, 0.f};
        xr0 = *(const float2*)&X[(size_t)(row0 + 0) * CH + lane * 2];
        if (nr > 1) xr1 = *(const float2*)&X[(size_t)(row0 + 1) * CH + lane * 2];
        if (nr > 2) xr2 = *(const float2*)&X[(size_t)(row0 + 2) * CH + lane * 2];
        if (nr > 3) xr3 = *(const float2*)&X[(size_t)(row0 + 3) * CH + lane * 2];
        float2 a0 = {0.f,0.f}, a1 = {0.f,0.f}, a2 = {0.f,0.f}, a3 = {0.f,0.f};
#pragma unroll 4
        for (int m = 0; m < 64; m++) {
            float2 wA = *(float2*)&Wl[(2 * m) * CH + lane * 2];
            float2 wB = *(float2*)&Wl[(2 * m + 1) * CH + lane * 2];
            float x0a = __shfl(xr0.x, m), x0b = __shfl(xr0.y, m);
            float x1a = __shfl(xr1.x, m), x1b = __shfl(xr1.y, m);
            float x2a = __shfl(xr2.x, m), x2b = __shfl(xr2.y, m);
            float x3a = __shfl(xr3.x, m), x3b = __shfl(xr3.y, m);
            a0.x = fmaf(x0a, wA.x, a0.x); a0.y = fmaf(x0a, wA.y, a0.y);
            a0.x = fmaf(x0b, wB.x, a0.x); a0.y = fmaf(x0b, wB.y, a0.y);
            a1.x = fmaf(x1a, wA.x, a1.x); a1.y = fmaf(x1a, wA.y, a1.y);
            a1.x = fmaf(x1b, wB.x, a1.x); a1.y = fmaf(x1b, wB.y, a1.y);
            a2.x = fmaf(x2a, wA.x, a2.x); a2.y = fmaf(x2a, wA.y, a2.y);
            a2.x = fmaf(x2b, wB.x, a2.x); a2.y = fmaf(x2b, wB.y, a2.y);
            a3.x = fmaf(x3a, wA.x, a3.x); a3.y = fmaf(x3a, wA.y, a3.y);
            a3.x = fmaf(x3b, wB.x, a3.x); a3.y = fmaf(x3b, wB.y, a3.y);
        }
        *(float2*)&H[(size_t)(row0 + 0) * CH + lane * 2] = a0;
        if (nr > 1) *(float2*)&H[(size_t)(row0 + 1) * CH + lane * 2] = a1;
        if (nr > 2) *(float2*)&H[(size_t)(row0 + 2) * CH + lane * 2] = a2;
        if (nr > 3) *(float2*)&H[(size_t)(row0 + 3) * CH + lane * 2] = a3;
    }
}

// ---------------- GCN aggregation + bias + GraphNorm stats ----------------
__launch_bounds__(256)
__global__ void k_gcn_agg(const float* __restrict__ H, const int* __restrict__ csr,
                          const int* __restrict__ rowptr, const float* __restrict__ dinv,
                          const float* __restrict__ b1, float* __restrict__ T, float* __restrict__ stats) {
    int t = threadIdx.x, wave = t >> 6, lane = t & 63;
    float2 bias = *(const float2*)&b1[lane * 2];
    float2 ssum = {0.f, 0.f}, ssq = {0.f, 0.f};
    for (int node = blockIdx.x * 4 + wave; node < NN; node += gridDim.x * 4) {
        int beg = rowptr[node], end = rowptr[node + 1];
        float di = dinv[node];
        float2 acc = {0.f, 0.f};
        for (int k = beg; k < end; k++) {
            int s = csr[k];
            float w = di * dinv[s];
            float2 hv = *(const float2*)&H[(size_t)s * CH + lane * 2];
            acc.x = fmaf(w, hv.x, acc.x); acc.y = fmaf(w, hv.y, acc.y);
        }
        float2 tv = {acc.x + bias.x, acc.y + bias.y};
        *(float2*)&T[(size_t)node * CH + lane * 2] = tv;
        ssum.x += tv.x; ssum.y += tv.y;
        ssq.x = fmaf(tv.x, tv.x, ssq.x); ssq.y = fmaf(tv.y, tv.y, ssq.y);
    }
    __shared__ float red[4][64][4];
    red[wave][lane][0] = ssum.x; red[wave][lane][1] = ssum.y;
    red[wave][lane][2] = ssq.x;  red[wave][lane][3] = ssq.y;
    __syncthreads();
    if (wave == 0) {
        float v0 = 0.f, v1 = 0.f, v2 = 0.f, v3 = 0.f;
        for (int w2 = 0; w2 < 4; w2++) {
            v0 += red[w2][lane][0]; v1 += red[w2][lane][1];
            v2 += red[w2][lane][2]; v3 += red[w2][lane][3];
        }
        float* bank = stats + (blockIdx.x & 7) * 256;
        atomicAdd(&bank[2 * lane], v0);
        atomicAdd(&bank[2 * lane + 1], v1);
        atomicAdd(&bank[128 + 2 * lane], v2);
        atomicAdd(&bank[128 + 2 * lane + 1], v3);
    }
}

// ---------------- GraphNorm finalize: alpha/beta per channel ----------------
__global__ void k_fin(const float* __restrict__ stats, const float* __restrict__ gw,
                      const float* __restrict__ gb, const float* __restrict__ gms,
                      float* __restrict__ alpha, float* __restrict__ beta) {
    int c = threadIdx.x;  // 128 threads
    float s = 0.f, q = 0.f;
    for (int b = 0; b < 8; b++) { s += stats[b * 256 + c]; q += stats[b * 256 + 128 + c]; }
    float mean = s * (1.f / NN);
    float ctr = gms[c] * mean;
    float var = q * (1.f / NN) - 2.f * ctr * mean + ctr * ctr;
    float al = gw[c] * rsqrtf(var + EPSV);
    alpha[c] = al;
    beta[c] = gb[c] - al * ctr;
}

// ---------------- GEMM 2 (fused): x1 = x + lrelu(a1*T+b1); H=x1@Wg; a_s,a_d ----------------
__launch_bounds__(256, 2)
__global__ void k_gemm2(const float* __restrict__ X, const float* __restrict__ T,
                        const float* __restrict__ W, const float* __restrict__ alpha,
                        const float* __restrict__ beta, const float* __restrict__ attS,
                        const float* __restrict__ attD, float* __restrict__ X1out,
                        float* __restrict__ H, float* __restrict__ a_s, float* __restrict__ a_d) {
    __shared__ float Wl[CH * CH];
    int t = threadIdx.x;
    for (int i = t * 4; i < CH * CH; i += 1024) *(float4*)&Wl[i] = *(const float4*)&W[i];
    __syncthreads();
    int wave = t >> 6, lane = t & 63;
    float2 al = *(const float2*)&alpha[lane * 2];
    float2 be = *(const float2*)&beta[lane * 2];
    float2 as2 = *(const float2*)&attS[lane * 2];
    float2 ad2 = *(const float2*)&attD[lane * 2];
    for (int row0 = blockIdx.x * 16 + wave * 4; row0 < NN; row0 += gridDim.x * 16) {
        int nr = NN - row0; if (nr > 4) nr = 4;
        float2 xr[4];
#pragma unroll
        for (int r = 0; r < 4; r++) { xr[r].x = 0.f; xr[r].y = 0.f; }
        for (int r = 0; r < nr; r++) {
            size_t idx = (size_t)(row0 + r) * CH + lane * 2;
            float2 xv = *(const float2*)&X[idx];
            float2 tv = *(const float2*)&T[idx];
            float2 x1;
            x1.x = xv.x + lrelu(fmaf(al.x, tv.x, be.x), 0.01f);
            x1.y = xv.y + lrelu(fmaf(al.y, tv.y, be.y), 0.01f);
            *(float2*)&X1out[idx] = x1;
            xr[r] = x1;
        }
        float2 a0 = {0.f,0.f}, a1 = {0.f,0.f}, a2 = {0.f,0.f}, a3 = {0.f,0.f};
#pragma unroll 4
        for (int m = 0; m < 64; m++) {
            float2 wA = *(float2*)&Wl[(2 * m) * CH + lane * 2];
            float2 wB = *(float2*)&Wl[(2 * m + 1) * CH + lane * 2];
            float x0a = __shfl(xr[0].x, m), x0b = __shfl(xr[0].y, m);
            float x1a = __shfl(xr[1].x, m), x1b = __shfl(xr[1].y, m);
            float x2a = __shfl(xr[2].x, m), x2b = __shfl(xr[2].y, m);
            float x3a = __shfl(xr[3].x, m), x3b = __shfl(xr[3].y, m);
            a0.x = fmaf(x0a, wA.x, a0.x); a0.y = fmaf(x0a, wA.y, a0.y);
            a0.x = fmaf(x0b, wB.x, a0.x); a0.y = fmaf(x0b, wB.y, a0.y);
            a1.x = fmaf(x1a, wA.x, a1.x); a1.y = fmaf(x1a, wA.y, a1.y);
            a1.x = fmaf(x1b, wB.x, a1.x); a1.y = fmaf(x1b, wB.y, a1.y);
            a2.x = fmaf(x2a, wA.x, a2.x); a2.y = fmaf(x2a, wA.y, a2.y);
            a2.x = fmaf(x2b, wB.x, a2.x); a2.y = fmaf(x2b, wB.y, a2.y);
            a3.x = fmaf(x3a, wA.x, a3.x); a3.y = fmaf(x3a, wA.y, a3.y);
            a3.x = fmaf(x3b, wB.x, a3.x); a3.y = fmaf(x3b, wB.y, a3.y);
        }
        float2 aa[4] = {a0, a1, a2, a3};
        for (int r = 0; r < nr; r++) {
            *(float2*)&H[(size_t)(row0 + r) * CH + lane * 2] = aa[r];
            float ps = fmaf(aa[r].x, as2.x, aa[r].y * as2.y);
            float pd = fmaf(aa[r].x, ad2.x, aa[r].y * ad2.y);
            for (int off = 32; off > 0; off >>= 1) {
                ps += __shfl_xor(ps, off);
                pd += __shfl_xor(pd, off);
            }
            if (lane == 0) { a_s[row0 + r] = ps; a_d[row0 + r] = pd; }
        }
    }
}

// ---------------- GAT aggregation (softmax over in-edges) + bias + stats ----------------
__launch_bounds__(256)
__global__ void k_gat_agg(const float* __restrict__ H, const int* __restrict__ csr,
                          const int* __restrict__ rowptr, const float* __restrict__ a_s,
                          const float* __restrict__ a_d, const float* __restrict__ bg,
                          float* __restrict__ T, float* __restrict__ stats) {
    int t = threadIdx.x, wave = t >> 6, lane = t & 63;
    float2 bias = *(const float2*)&bg[lane * 2];
    float2 ssum = {0.f, 0.f}, ssq = {0.f, 0.f};
    for (int node = blockIdx.x * 4 + wave; node < NN; node += gridDim.x * 4) {
        int beg = rowptr[node], end = rowptr[node + 1];
        float adI = a_d[node];
        // pass 1: max over edges (lane-strided)
        float m = -1e30f;
        for (int k = beg + lane; k < end; k += 64) {
            float e = lrelu(a_s[csr[k]] + adI, 0.2f);
            m = fmaxf(m, e);
        }
        for (int off = 32; off > 0; off >>= 1) m = fmaxf(m, __shfl_xor(m, off));
        // pass 2: weighted accumulate (whole wave per edge)
        float den = 0.f;
        float2 acc = {0.f, 0.f};
        for (int k = beg; k < end; k++) {
            int s = csr[k];
            float e = lrelu(a_s[s] + adI, 0.2f);
            float wgt = __expf(e - m);
            den += wgt;
            float2 hv = *(const float2*)&H[(size_t)s * CH + lane * 2];
            acc.x = fmaf(wgt, hv.x, acc.x); acc.y = fmaf(wgt, hv.y, acc.y);
        }
        float inv = 1.f / den;
        float2 tv = {fmaf(acc.x, inv, bias.x), fmaf(acc.y, inv, bias.y)};
        *(float2*)&T[(size_t)node * CH + lane * 2] = tv;
        ssum.x += tv.x; ssum.y += tv.y;
        ssq.x = fmaf(tv.x, tv.x, ssq.x); ssq.y = fmaf(tv.y, tv.y, ssq.y);
    }
    __shared__ float red[4][64][4];
    red[wave][lane][0] = ssum.x; red[wave][lane][1] = ssum.y;
    red[wave][lane][2] = ssq.x;  red[wave][lane][3] = ssq.y;
    __syncthreads();
    if (wave == 0) {
        float v0 = 0.f, v1 = 0.f, v2 = 0.f, v3 = 0.f;
        for (int w2 = 0; w2 < 4; w2++) {
            v0 += red[w2][lane][0]; v1 += red[w2][lane][1];
            v2 += red[w2][lane][2]; v3 += red[w2][lane][3];
        }
        float* bank = stats + (blockIdx.x & 7) * 256;
        atomicAdd(&bank[2 * lane], v0);
        atomicAdd(&bank[2 * lane + 1], v1);
        atomicAdd(&bank[128 + 2 * lane], v2);
        atomicAdd(&bank[128 + 2 * lane + 1], v3);
    }
}

// ---------------- final: out = x1 + lrelu(a2*T2+b2) ----------------
__global__ void k_final(const float* __restrict__ T, const float* __restrict__ alpha,
                        const float* __restrict__ beta, float* __restrict__ out) {
    size_t i = (size_t)(blockIdx.x * 256 + threadIdx.x) * 4;
    if (i >= (size_t)NN * CH) return;
    int c = (int)(i & (CH - 1));
    float4 tv = *(const float4*)&T[i];
    float4 av = *(const float4*)&alpha[c];
    float4 bv = *(const float4*)&beta[c];
    float4 o = *(float4*)&out[i];
    o.x += lrelu(fmaf(av.x, tv.x, bv.x), 0.01f);
    o.y += lrelu(fmaf(av.y, tv.y, bv.y), 0.01f);
    o.z += lrelu(fmaf(av.z, tv.z, bv.z), 0.01f);
    o.w += lrelu(fmaf(av.w, tv.w, bv.w), 0.01f);
    *(float4*)&out[i] = o;
}

extern "C" void kernel_launch(void* const* d_in, const int* in_sizes, int n_in,
                              void* d_out, int out_size, void* d_ws, size_t ws_size,
                              hipStream_t stream) {
    const float* x    = (const float*)d_in[0];
    const int*   edges= (const int*)d_in[1];
    const float* W1   = (const float*)d_in[2];
    const float* b1   = (const float*)d_in[3];
    const float* gw   = (const float*)d_in[4];
    const float* gb   = (const float*)d_in[5];
    const float* gms  = (const float*)d_in[6];
    const float* Wg   = (const float*)d_in[7];
    const float* bg   = (const float*)d_in[8];
    const float* attS = (const float*)d_in[9];
    const float* attD = (const float*)d_in[10];
    float* out = (float*)d_out;

    char* w = (char*)d_ws;
    size_t o = 0;
    float* H      = (float*)(w + o); o += (size_t)NN * CH * 4;      // 51.2 MB
    float* T      = (float*)(w + o); o += (size_t)NN * CH * 4;      // 51.2 MB
    int*   csr    = (int*)(w + o);   o += (size_t)TOTE * 4;         // 6.8 MB
    int*   rowptr = (int*)(w + o);   o += (size_t)(NN + 64) * 4;
    int*   deg    = (int*)(w + o);   o += (size_t)NN * 4;
    int*   cursor = (int*)(w + o);   o += (size_t)NN * 4;
    float* dinv   = (float*)(w + o); o += (size_t)NN * 4;
    float* a_s    = (float*)(w + o); o += (size_t)NN * 4;
    float* a_d    = (float*)(w + o); o += (size_t)NN * 4;
    int*   bsum   = (int*)(w + o);   o += 512;
    int*   boff   = (int*)(w + o);   o += 512;
    float* stats  = (float*)(w + o); o += 4096 * 4;                 // [2 stages][8 banks][256]
    float* alpha1 = (float*)(w + o); o += 512;
    float* beta1  = (float*)(w + o); o += 512;
    float* alpha2 = (float*)(w + o); o += 512;
    float* beta2  = (float*)(w + o); o += 512;

    k_init <<<(NN + 255) / 256, 256, 0, stream>>>(deg, cursor, stats);
    k_count<<<(NE + 255) / 256, 256, 0, stream>>>(edges, deg);
    k_scan1<<<NB, 256, 0, stream>>>(deg, bsum, dinv);
    k_scan2<<<1, 32, 0, stream>>>(bsum, boff);
    k_scan3<<<NB, 256, 0, stream>>>(deg, boff, rowptr);
    k_fill <<<(TOTE + 255) / 256, 256, 0, stream>>>(edges, rowptr, cursor, csr);

    k_gemm1  <<<512, 256, 0, stream>>>(x, W1, H);
    k_gcn_agg<<<2048, 256, 0, stream>>>(H, csr, rowptr, dinv, b1, T, stats);
    k_fin    <<<1, 128, 0, stream>>>(stats, gw, gb, gms, alpha1, beta1);

    k_gemm2  <<<512, 256, 0, stream>>>(x, T, Wg, alpha1, beta1, attS, attD, out, H, a_s, a_d);
    k_gat_agg<<<2048, 256, 0, stream>>>(H, csr, rowptr, a_s, a_d, bg, T, stats + 2048);
    k_fin    <<<1, 128, 0, stream>>>(stats + 2048, gw, gb, gms, alpha2, beta2);

    k_final<<<(NN * CH / 4 + 255) / 256, 256, 0, stream>>>(T, alpha2, beta2, out);
}

// Round 2
// 917.825 us; speedup vs baseline: 1.1230x; 1.1230x over previous
//
#include <hip/hip_runtime.h>
#include <math.h>

#define NN 100000
#define NE 1600000
#define CH 128
#define TOTE (NE + NN)
#define EPSV 1e-5f
#define NB 98  // ceil(NN/1024)
#define BM 128
#define BK 32
#define NGB 782  // ceil(NN/BM)

__device__ __forceinline__ float lrelu(float v, float s) { return v < 0.f ? v * s : v; }

// ---------------- CSR build ----------------
__global__ void k_init(int* __restrict__ deg, int* __restrict__ cursor, float* __restrict__ stats) {
    int i = blockIdx.x * 256 + threadIdx.x;
    if (i < NN) { deg[i] = 1; cursor[i] = 0; }   // deg=1 accounts for the self-loop
    if (i < 4096) stats[i] = 0.f;                 // both stages' stat banks
}

__global__ void k_count(const int* __restrict__ edges, int* __restrict__ deg) {
    int i = blockIdx.x * 256 + threadIdx.x;
    if (i < NE) atomicAdd(&deg[edges[NE + i]], 1);
}

__global__ void k_scan1(const int* __restrict__ deg, int* __restrict__ bsum, float* __restrict__ dinv) {
    __shared__ int red[256];
    int t = threadIdx.x;
    int base = blockIdx.x * 1024 + t * 4;
    int s = 0;
#pragma unroll
    for (int j = 0; j < 4; j++) {
        int i = base + j;
        if (i < NN) { int d = deg[i]; s += d; dinv[i] = rsqrtf((float)d); }
    }
    red[t] = s; __syncthreads();
    for (int off = 128; off > 0; off >>= 1) { if (t < off) red[t] += red[t + off]; __syncthreads(); }
    if (t == 0) bsum[blockIdx.x] = red[0];
}

__global__ void k_scan2(const int* __restrict__ bsum, int* __restrict__ boff) {
    if (threadIdx.x == 0) {
        int acc = 0;
        for (int b = 0; b < NB; b++) { boff[b] = acc; acc += bsum[b]; }
    }
}

__global__ void k_scan3(const int* __restrict__ deg, const int* __restrict__ boff, int* __restrict__ rowptr) {
    __shared__ int sc[256];
    int t = threadIdx.x;
    int base = blockIdx.x * 1024 + t * 4;
    int d[4];
#pragma unroll
    for (int j = 0; j < 4; j++) { int i = base + j; d[j] = (i < NN) ? deg[i] : 0; }
    int local = d[0] + d[1] + d[2] + d[3];
    sc[t] = local; __syncthreads();
    for (int off = 1; off < 256; off <<= 1) {
        int v = (t >= off) ? sc[t - off] : 0;
        __syncthreads();
        sc[t] += v;
        __syncthreads();
    }
    int run = sc[t] - local + boff[blockIdx.x];
#pragma unroll
    for (int j = 0; j < 4; j++) {
        int i = base + j;
        if (i < NN) { rowptr[i] = run; run += d[j]; }
    }
    if (blockIdx.x == 0 && t == 0) rowptr[NN] = TOTE;
}

__global__ void k_fill(const int* __restrict__ edges, const int* __restrict__ rowptr,
                       int* __restrict__ cursor, int* __restrict__ csr) {
    int i = blockIdx.x * 256 + threadIdx.x;
    if (i < NE) {
        int s = edges[i], d = edges[NE + i];
        int pos = atomicAdd(&cursor[d], 1);
        csr[rowptr[d] + pos] = s;
    } else if (i < TOTE) {
        int v = i - NE;
        int pos = atomicAdd(&cursor[v], 1);
        csr[rowptr[v] + pos] = v;   // self-loop
    }
}

// ---------------- GEMM 1: H = X @ W1 ----------------
// lane=row design: wave w -> (row-half = w&1, col-half = w>>1); lane owns one row,
// 64 accumulators (its col-half). X chunk transposed in LDS (conflict-free b32 reads);
// W rows are wave-uniform -> scalar loads (s_load) via readfirstlane'd base.
__launch_bounds__(256, 4)
__global__ void k_gemm1(const float* __restrict__ X, const float* __restrict__ W, float* __restrict__ H) {
    __shared__ float Xl[BK][BM + 1];
    int t = threadIdx.x, wave = t >> 6, lane = t & 63;
    int rhalf = wave & 1;
    int coff = __builtin_amdgcn_readfirstlane((wave >> 1) * 64);
    int row0 = blockIdx.x * BM;
    int row = row0 + rhalf * 64 + lane;
    float acc[64];
#pragma unroll
    for (int c = 0; c < 64; c++) acc[c] = 0.f;
    for (int kc = 0; kc < CH; kc += BK) {
        __syncthreads();
#pragma unroll
        for (int q = 0; q < 4; ++q) {
            int p = t + 256 * q;
            int r = p >> 3, m = p & 7;
            int gr = row0 + r;
            float4 v = {0.f, 0.f, 0.f, 0.f};
            if (gr < NN) v = *(const float4*)&X[(size_t)gr * CH + kc + 4 * m];
            Xl[4 * m + 0][r] = v.x; Xl[4 * m + 1][r] = v.y;
            Xl[4 * m + 2][r] = v.z; Xl[4 * m + 3][r] = v.w;
        }
        __syncthreads();
#pragma unroll 4
        for (int k = 0; k < BK; ++k) {
            float xv = Xl[k][rhalf * 64 + lane];
            const float* Wr = W + (size_t)(kc + k) * CH + coff;
#pragma unroll
            for (int c = 0; c < 64; ++c) acc[c] = fmaf(xv, Wr[c], acc[c]);
        }
    }
    if (row < NN) {
        float* Hp = H + (size_t)row * CH + coff;
#pragma unroll
        for (int c = 0; c < 64; c += 4) {
            float4 v = {acc[c], acc[c + 1], acc[c + 2], acc[c + 3]};
            *(float4*)&Hp[c] = v;
        }
    }
}

// ---------------- GCN aggregation + bias + GraphNorm stats ----------------
__launch_bounds__(256)
__global__ void k_gcn_agg(const float* __restrict__ H, const int* __restrict__ csr,
                          const int* __restrict__ rowptr, const float* __restrict__ dinv,
                          const float* __restrict__ b1, float* __restrict__ T, float* __restrict__ stats) {
    int t = threadIdx.x, wave = t >> 6, lane = t & 63;
    float2 bias = *(const float2*)&b1[lane * 2];
    float2 ssum = {0.f, 0.f}, ssq = {0.f, 0.f};
    for (int node = blockIdx.x * 4 + wave; node < NN; node += gridDim.x * 4) {
        int beg = rowptr[node], end = rowptr[node + 1];
        float di = dinv[node];
        float2 acc = {0.f, 0.f};
        for (int k = beg; k < end; k++) {
            int s = csr[k];
            float w = di * dinv[s];
            float2 hv = *(const float2*)&H[(size_t)s * CH + lane * 2];
            acc.x = fmaf(w, hv.x, acc.x); acc.y = fmaf(w, hv.y, acc.y);
        }
        float2 tv = {acc.x + bias.x, acc.y + bias.y};
        *(float2*)&T[(size_t)node * CH + lane * 2] = tv;
        ssum.x += tv.x; ssum.y += tv.y;
        ssq.x = fmaf(tv.x, tv.x, ssq.x); ssq.y = fmaf(tv.y, tv.y, ssq.y);
    }
    __shared__ float red[4][64][4];
    red[wave][lane][0] = ssum.x; red[wave][lane][1] = ssum.y;
    red[wave][lane][2] = ssq.x;  red[wave][lane][3] = ssq.y;
    __syncthreads();
    if (wave == 0) {
        float v0 = 0.f, v1 = 0.f, v2 = 0.f, v3 = 0.f;
        for (int w2 = 0; w2 < 4; w2++) {
            v0 += red[w2][lane][0]; v1 += red[w2][lane][1];
            v2 += red[w2][lane][2]; v3 += red[w2][lane][3];
        }
        float* bank = stats + (blockIdx.x & 7) * 256;
        atomicAdd(&bank[2 * lane], v0);
        atomicAdd(&bank[2 * lane + 1], v1);
        atomicAdd(&bank[128 + 2 * lane], v2);
        atomicAdd(&bank[128 + 2 * lane + 1], v3);
    }
}

// ---------------- GraphNorm finalize: alpha/beta per channel ----------------
__global__ void k_fin(const float* __restrict__ stats, const float* __restrict__ gw,
                      const float* __restrict__ gb, const float* __restrict__ gms,
                      float* __restrict__ alpha, float* __restrict__ beta) {
    int c = threadIdx.x;  // 128 threads
    float s = 0.f, q = 0.f;
    for (int b = 0; b < 8; b++) { s += stats[b * 256 + c]; q += stats[b * 256 + 128 + c]; }
    float mean = s * (1.f / NN);
    float ctr = gms[c] * mean;
    float var = q * (1.f / NN) - 2.f * ctr * mean + ctr * ctr;
    float al = gw[c] * rsqrtf(var + EPSV);
    alpha[c] = al;
    beta[c] = gb[c] - al * ctr;
}

// ---------------- GEMM 2 (fused): x1 = x + lrelu(a1*T+b1); H=x1@Wg; a_s,a_d ----------------
__launch_bounds__(256, 4)
__global__ void k_gemm2(const float* __restrict__ X, const float* __restrict__ T,
                        const float* __restrict__ W, const float* __restrict__ alpha,
                        const float* __restrict__ beta, const float* __restrict__ attS,
                        const float* __restrict__ attD, float* __restrict__ X1out,
                        float* __restrict__ H, float* __restrict__ a_s, float* __restrict__ a_d) {
    __shared__ float Xl[BK][BM + 1];
    int t = threadIdx.x, wave = t >> 6, lane = t & 63;
    int rhalf = wave & 1;
    int chalf = wave >> 1;
    int coff = __builtin_amdgcn_readfirstlane(chalf * 64);
    int row0 = blockIdx.x * BM;
    int row = row0 + rhalf * 64 + lane;
    float acc[64];
#pragma unroll
    for (int c = 0; c < 64; c++) acc[c] = 0.f;
    for (int kc = 0; kc < CH; kc += BK) {
        __syncthreads();
#pragma unroll
        for (int q = 0; q < 4; ++q) {
            int p = t + 256 * q;
            int r = p >> 3, m = p & 7;
            int gr = row0 + r;
            float4 v = {0.f, 0.f, 0.f, 0.f};
            if (gr < NN) {
                size_t idx = (size_t)gr * CH + kc + 4 * m;
                float4 xv = *(const float4*)&X[idx];
                float4 tv = *(const float4*)&T[idx];
                float4 al = *(const float4*)&alpha[kc + 4 * m];
                float4 be = *(const float4*)&beta[kc + 4 * m];
                v.x = xv.x + lrelu(fmaf(al.x, tv.x, be.x), 0.01f);
                v.y = xv.y + lrelu(fmaf(al.y, tv.y, be.y), 0.01f);
                v.z = xv.z + lrelu(fmaf(al.z, tv.z, be.z), 0.01f);
                v.w = xv.w + lrelu(fmaf(al.w, tv.w, be.w), 0.01f);
                *(float4*)&X1out[idx] = v;
            }
            Xl[4 * m + 0][r] = v.x; Xl[4 * m + 1][r] = v.y;
            Xl[4 * m + 2][r] = v.z; Xl[4 * m + 3][r] = v.w;
        }
        __syncthreads();
#pragma unroll 4
        for (int k = 0; k < BK; ++k) {
            float xv = Xl[k][rhalf * 64 + lane];
            const float* Wr = W + (size_t)(kc + k) * CH + coff;
#pragma unroll
            for (int c = 0; c < 64; ++c) acc[c] = fmaf(xv, Wr[c], acc[c]);
        }
    }
    // store H + attention partial dots
    float ps = 0.f, pd = 0.f;
    {
        const float* As = attS + coff;
        const float* Ad = attD + coff;
        if (row < NN) {
            float* Hp = H + (size_t)row * CH + coff;
#pragma unroll
            for (int c = 0; c < 64; c += 4) {
                float4 v = {acc[c], acc[c + 1], acc[c + 2], acc[c + 3]};
                *(float4*)&Hp[c] = v;
            }
        }
#pragma unroll
        for (int c = 0; c < 64; ++c) {
            ps = fmaf(acc[c], As[c], ps);
            pd = fmaf(acc[c], Ad[c], pd);
        }
    }
    // cross-wave (col-half) combine through LDS (reuse Xl)
    float* red = (float*)Xl;
    __syncthreads();
    if (chalf == 0) {
        red[rhalf * 64 + lane] = ps;
        red[128 + rhalf * 64 + lane] = pd;
    }
    __syncthreads();
    if (chalf == 1 && row < NN) {
        a_s[row] = ps + red[rhalf * 64 + lane];
        a_d[row] = pd + red[128 + rhalf * 64 + lane];
    }
}

// ---------------- GAT aggregation (softmax over in-edges) + bias + stats ----------------
__launch_bounds__(256)
__global__ void k_gat_agg(const float* __restrict__ H, const int* __restrict__ csr,
                          const int* __restrict__ rowptr, const float* __restrict__ a_s,
                          const float* __restrict__ a_d, const float* __restrict__ bg,
                          float* __restrict__ T, float* __restrict__ stats) {
    int t = threadIdx.x, wave = t >> 6, lane = t & 63;
    float2 bias = *(const float2*)&bg[lane * 2];
    float2 ssum = {0.f, 0.f}, ssq = {0.f, 0.f};
    for (int node = blockIdx.x * 4 + wave; node < NN; node += gridDim.x * 4) {
        int beg = rowptr[node], end = rowptr[node + 1];
        float adI = a_d[node];
        float m = -1e30f;
        for (int k = beg + lane; k < end; k += 64) {
            float e = lrelu(a_s[csr[k]] + adI, 0.2f);
            m = fmaxf(m, e);
        }
        for (int off = 32; off > 0; off >>= 1) m = fmaxf(m, __shfl_xor(m, off));
        float den = 0.f;
        float2 acc = {0.f, 0.f};
        for (int k = beg; k < end; k++) {
            int s = csr[k];
            float e = lrelu(a_s[s] + adI, 0.2f);
            float wgt = __expf(e - m);
            den += wgt;
            float2 hv = *(const float2*)&H[(size_t)s * CH + lane * 2];
            acc.x = fmaf(wgt, hv.x, acc.x); acc.y = fmaf(wgt, hv.y, acc.y);
        }
        float inv = 1.f / den;
        float2 tv = {fmaf(acc.x, inv, bias.x), fmaf(acc.y, inv, bias.y)};
        *(float2*)&T[(size_t)node * CH + lane * 2] = tv;
        ssum.x += tv.x; ssum.y += tv.y;
        ssq.x = fmaf(tv.x, tv.x, ssq.x); ssq.y = fmaf(tv.y, tv.y, ssq.y);
    }
    __shared__ float red[4][64][4];
    red[wave][lane][0] = ssum.x; red[wave][lane][1] = ssum.y;
    red[wave][lane][2] = ssq.x;  red[wave][lane][3] = ssq.y;
    __syncthreads();
    if (wave == 0) {
        float v0 = 0.f, v1 = 0.f, v2 = 0.f, v3 = 0.f;
        for (int w2 = 0; w2 < 4; w2++) {
            v0 += red[w2][lane][0]; v1 += red[w2][lane][1];
            v2 += red[w2][lane][2]; v3 += red[w2][lane][3];
        }
        float* bank = stats + (blockIdx.x & 7) * 256;
        atomicAdd(&bank[2 * lane], v0);
        atomicAdd(&bank[2 * lane + 1], v1);
        atomicAdd(&bank[128 + 2 * lane], v2);
        atomicAdd(&bank[128 + 2 * lane + 1], v3);
    }
}

// ---------------- final: out = x1 + lrelu(a2*T2+b2) ----------------
__global__ void k_final(const float* __restrict__ T, const float* __restrict__ alpha,
                        const float* __restrict__ beta, float* __restrict__ out) {
    size_t i = (size_t)(blockIdx.x * 256 + threadIdx.x) * 4;
    if (i >= (size_t)NN * CH) return;
    int c = (int)(i & (CH - 1));
    float4 tv = *(const float4*)&T[i];
    float4 av = *(const float4*)&alpha[c];
    float4 bv = *(const float4*)&beta[c];
    float4 o = *(float4*)&out[i];
    o.x += lrelu(fmaf(av.x, tv.x, bv.x), 0.01f);
    o.y += lrelu(fmaf(av.y, tv.y, bv.y), 0.01f);
    o.z += lrelu(fmaf(av.z, tv.z, bv.z), 0.01f);
    o.w += lrelu(fmaf(av.w, tv.w, bv.w), 0.01f);
    *(float4*)&out[i] = o;
}

extern "C" void kernel_launch(void* const* d_in, const int* in_sizes, int n_in,
                              void* d_out, int out_size, void* d_ws, size_t ws_size,
                              hipStream_t stream) {
    const float* x    = (const float*)d_in[0];
    const int*   edges= (const int*)d_in[1];
    const float* W1   = (const float*)d_in[2];
    const float* b1   = (const float*)d_in[3];
    const float* gw   = (const float*)d_in[4];
    const float* gb   = (const float*)d_in[5];
    const float* gms  = (const float*)d_in[6];
    const float* Wg   = (const float*)d_in[7];
    const float* bg   = (const float*)d_in[8];
    const float* attS = (const float*)d_in[9];
    const float* attD = (const float*)d_in[10];
    float* out = (float*)d_out;

    char* w = (char*)d_ws;
    size_t o = 0;
    float* H      = (float*)(w + o); o += (size_t)NN * CH * 4;      // 51.2 MB
    float* T      = (float*)(w + o); o += (size_t)NN * CH * 4;      // 51.2 MB
    int*   csr    = (int*)(w + o);   o += (size_t)TOTE * 4;         // 6.8 MB
    int*   rowptr = (int*)(w + o);   o += (size_t)(NN + 64) * 4;
    int*   deg    = (int*)(w + o);   o += (size_t)NN * 4;
    int*   cursor = (int*)(w + o);   o += (size_t)NN * 4;
    float* dinv   = (float*)(w + o); o += (size_t)NN * 4;
    float* a_s    = (float*)(w + o); o += (size_t)NN * 4;
    float* a_d    = (float*)(w + o); o += (size_t)NN * 4;
    int*   bsum   = (int*)(w + o);   o += 512;
    int*   boff   = (int*)(w + o);   o += 512;
    float* stats  = (float*)(w + o); o += 4096 * 4;                 // [2 stages][8 banks][256]
    float* alpha1 = (float*)(w + o); o += 512;
    float* beta1  = (float*)(w + o); o += 512;
    float* alpha2 = (float*)(w + o); o += 512;
    float* beta2  = (float*)(w + o); o += 512;

    k_init <<<(NN + 255) / 256, 256, 0, stream>>>(deg, cursor, stats);
    k_count<<<(NE + 255) / 256, 256, 0, stream>>>(edges, deg);
    k_scan1<<<NB, 256, 0, stream>>>(deg, bsum, dinv);
    k_scan2<<<1, 32, 0, stream>>>(bsum, boff);
    k_scan3<<<NB, 256, 0, stream>>>(deg, boff, rowptr);
    k_fill <<<(TOTE + 255) / 256, 256, 0, stream>>>(edges, rowptr, cursor, csr);

    k_gemm1  <<<NGB, 256, 0, stream>>>(x, W1, H);
    k_gcn_agg<<<2048, 256, 0, stream>>>(H, csr, rowptr, dinv, b1, T, stats);
    k_fin    <<<1, 128, 0, stream>>>(stats, gw, gb, gms, alpha1, beta1);

    k_gemm2  <<<NGB, 256, 0, stream>>>(x, T, Wg, alpha1, beta1, attS, attD, out, H, a_s, a_d);
    k_gat_agg<<<2048, 256, 0, stream>>>(H, csr, rowptr, a_s, a_d, bg, T, stats + 2048);
    k_fin    <<<1, 128, 0, stream>>>(stats + 2048, gw, gb, gms, alpha2, beta2);

    k_final<<<(NN * CH / 4 + 255) / 256, 256, 0, stream>>>(T, alpha2, beta2, out);
}

// Round 3
// 717.409 us; speedup vs baseline: 1.4367x; 1.2794x over previous
//
#include <hip/hip_runtime.h>
#include <math.h>

#define NN 100000
#define NE 1600000
#define CH 128
#define TOTE (NE + NN)
#define EPSV 1e-5f
#define NB 98   // ceil(NN/1024)
#define NGB 1563 // ceil(NN/64)

typedef __attribute__((ext_vector_type(8))) short short8;
typedef __attribute__((ext_vector_type(4))) float floatx4;

__device__ __forceinline__ float lrelu(float v, float s) { return v < 0.f ? v * s : v; }

__device__ __forceinline__ unsigned short f2bf(float f) {
    unsigned int u = __float_as_uint(f);
    u += 0x7FFF + ((u >> 16) & 1);   // round-to-nearest-even
    return (unsigned short)(u >> 16);
}

// ---------------- CSR build ----------------
__global__ void k_init(int* __restrict__ deg, int* __restrict__ cursor, float* __restrict__ stats) {
    int i = blockIdx.x * 256 + threadIdx.x;
    if (i < NN) { deg[i] = 1; cursor[i] = 0; }   // deg=1 accounts for the self-loop
    if (i < 4096) stats[i] = 0.f;
}

__global__ void k_count(const int* __restrict__ edges, int* __restrict__ deg) {
    int i = blockIdx.x * 256 + threadIdx.x;
    if (i < NE) atomicAdd(&deg[edges[NE + i]], 1);
}

__global__ void k_scan1(const int* __restrict__ deg, int* __restrict__ bsum, float* __restrict__ dinv) {
    __shared__ int red[256];
    int t = threadIdx.x;
    int base = blockIdx.x * 1024 + t * 4;
    int s = 0;
#pragma unroll
    for (int j = 0; j < 4; j++) {
        int i = base + j;
        if (i < NN) { int d = deg[i]; s += d; dinv[i] = rsqrtf((float)d); }
    }
    red[t] = s; __syncthreads();
    for (int off = 128; off > 0; off >>= 1) { if (t < off) red[t] += red[t + off]; __syncthreads(); }
    if (t == 0) bsum[blockIdx.x] = red[0];
}

__global__ void k_scan2(const int* __restrict__ bsum, int* __restrict__ boff) {
    if (threadIdx.x == 0) {
        int acc = 0;
        for (int b = 0; b < NB; b++) { boff[b] = acc; acc += bsum[b]; }
    }
}

__global__ void k_scan3(const int* __restrict__ deg, const int* __restrict__ boff, int* __restrict__ rowptr) {
    __shared__ int sc[256];
    int t = threadIdx.x;
    int base = blockIdx.x * 1024 + t * 4;
    int d[4];
#pragma unroll
    for (int j = 0; j < 4; j++) { int i = base + j; d[j] = (i < NN) ? deg[i] : 0; }
    int local = d[0] + d[1] + d[2] + d[3];
    sc[t] = local; __syncthreads();
    for (int off = 1; off < 256; off <<= 1) {
        int v = (t >= off) ? sc[t - off] : 0;
        __syncthreads();
        sc[t] += v;
        __syncthreads();
    }
    int run = sc[t] - local + boff[blockIdx.x];
#pragma unroll
    for (int j = 0; j < 4; j++) {
        int i = base + j;
        if (i < NN) { rowptr[i] = run; run += d[j]; }
    }
    if (blockIdx.x == 0 && t == 0) rowptr[NN] = TOTE;
}

__global__ void k_fill(const int* __restrict__ edges, const int* __restrict__ rowptr,
                       int* __restrict__ cursor, int* __restrict__ csr) {
    int i = blockIdx.x * 256 + threadIdx.x;
    if (i < NE) {
        int s = edges[i], d = edges[NE + i];
        int pos = atomicAdd(&cursor[d], 1);
        csr[rowptr[d] + pos] = s;
    } else if (i < TOTE) {
        int v = i - NE;
        int pos = atomicAdd(&cursor[v], 1);
        csr[rowptr[v] + pos] = v;   // self-loop
    }
}

// ---------------- W swizzle into MFMA B-fragment order (bf16) ----------------
// Wsw[((nt*4+ks)*64 + lane)*8 + j] = bf16(W[k][n]), k=ks*32+(lane>>4)*8+j, n=nt*16+(lane&15)
__global__ void k_wswz(const float* __restrict__ W1, const float* __restrict__ Wg,
                       unsigned short* __restrict__ Wsw1, unsigned short* __restrict__ Wsw2) {
    int t = blockIdx.x * 256 + threadIdx.x;
    if (t >= 16384) return;
    int j = t & 7, lane = (t >> 3) & 63, ks = (t >> 9) & 3, nt = t >> 11;
    int k = ks * 32 + (lane >> 4) * 8 + j;
    int n = nt * 16 + (lane & 15);
    Wsw1[t] = f2bf(W1[k * CH + n]);
    Wsw2[t] = f2bf(Wg[k * CH + n]);
}

// ---------------- GEMM 1: H(bf16) = X @ W1 via MFMA ----------------
__launch_bounds__(256, 4)
__global__ void k_gemm1(const float* __restrict__ X, const unsigned short* __restrict__ Wsw,
                        unsigned short* __restrict__ H) {
    __shared__ __align__(16) short Xl[64 * 136];
    int t = threadIdx.x, wave = t >> 6, lane = t & 63;
    int row0 = blockIdx.x * 64;
    {   // stage X tile -> bf16 LDS
        int r = t >> 2, q = t & 3;
        int gr = row0 + r;
        const float* Xr = X + (size_t)gr * CH;
#pragma unroll
        for (int j = 0; j < 4; j++) {
            int c0 = q * 32 + j * 8;
            float4 v0 = {0.f,0.f,0.f,0.f}, v1 = {0.f,0.f,0.f,0.f};
            if (gr < NN) { v0 = *(const float4*)&Xr[c0]; v1 = *(const float4*)&Xr[c0 + 4]; }
            short8 s;
            s[0]=f2bf(v0.x); s[1]=f2bf(v0.y); s[2]=f2bf(v0.z); s[3]=f2bf(v0.w);
            s[4]=f2bf(v1.x); s[5]=f2bf(v1.y); s[6]=f2bf(v1.z); s[7]=f2bf(v1.w);
            *(short8*)&Xl[r * 136 + c0] = s;
        }
    }
    __syncthreads();
    floatx4 acc[8];
#pragma unroll
    for (int nt = 0; nt < 8; nt++) acc[nt] = (floatx4){0.f, 0.f, 0.f, 0.f};
    int arow = wave * 16 + (lane & 15);
    int koff = (lane >> 4) * 8;
#pragma unroll
    for (int ks = 0; ks < 4; ks++) {
        short8 af = *(short8*)&Xl[arow * 136 + ks * 32 + koff];
#pragma unroll
        for (int nt = 0; nt < 8; nt++) {
            short8 bf = *(const short8*)&Wsw[((nt * 4 + ks) * 64 + lane) * 8];
            acc[nt] = __builtin_amdgcn_mfma_f32_16x16x32_bf16(af, bf, acc[nt], 0, 0, 0);
        }
    }
    int orow0 = row0 + wave * 16 + (lane >> 4) * 4;
    int ocol = lane & 15;
#pragma unroll
    for (int nt = 0; nt < 8; nt++) {
#pragma unroll
        for (int r = 0; r < 4; r++) {
            int row = orow0 + r;
            if (row < NN) H[(size_t)row * CH + nt * 16 + ocol] = f2bf(acc[nt][r]);
        }
    }
}

// ---------------- GCN aggregation + bias + GraphNorm stats (bf16 H) ----------------
__launch_bounds__(256)
__global__ void k_gcn_agg(const unsigned short* __restrict__ H, const int* __restrict__ csr,
                          const int* __restrict__ rowptr, const float* __restrict__ dinv,
                          const float* __restrict__ b1, float* __restrict__ T, float* __restrict__ stats) {
    int t = threadIdx.x, wave = t >> 6, lane = t & 63;
    float2 bias = *(const float2*)&b1[lane * 2];
    float2 ssum = {0.f, 0.f}, ssq = {0.f, 0.f};
    for (int node = blockIdx.x * 4 + wave; node < NN; node += gridDim.x * 4) {
        int beg = rowptr[node], end = rowptr[node + 1];
        float di = dinv[node];
        float2 acc = {0.f, 0.f};
        for (int k = beg; k < end; k++) {
            int s = csr[k];
            float w = di * dinv[s];
            unsigned int u = *(const unsigned int*)&H[(size_t)s * CH + lane * 2];
            float hx = __uint_as_float(u << 16);
            float hy = __uint_as_float(u & 0xFFFF0000u);
            acc.x = fmaf(w, hx, acc.x); acc.y = fmaf(w, hy, acc.y);
        }
        float2 tv = {acc.x + bias.x, acc.y + bias.y};
        *(float2*)&T[(size_t)node * CH + lane * 2] = tv;
        ssum.x += tv.x; ssum.y += tv.y;
        ssq.x = fmaf(tv.x, tv.x, ssq.x); ssq.y = fmaf(tv.y, tv.y, ssq.y);
    }
    __shared__ float red[4][64][4];
    red[wave][lane][0] = ssum.x; red[wave][lane][1] = ssum.y;
    red[wave][lane][2] = ssq.x;  red[wave][lane][3] = ssq.y;
    __syncthreads();
    if (wave == 0) {
        float v0 = 0.f, v1 = 0.f, v2 = 0.f, v3 = 0.f;
        for (int w2 = 0; w2 < 4; w2++) {
            v0 += red[w2][lane][0]; v1 += red[w2][lane][1];
            v2 += red[w2][lane][2]; v3 += red[w2][lane][3];
        }
        float* bank = stats + (blockIdx.x & 7) * 256;
        atomicAdd(&bank[2 * lane], v0);
        atomicAdd(&bank[2 * lane + 1], v1);
        atomicAdd(&bank[128 + 2 * lane], v2);
        atomicAdd(&bank[128 + 2 * lane + 1], v3);
    }
}

// ---------------- GraphNorm finalize ----------------
__global__ void k_fin(const float* __restrict__ stats, const float* __restrict__ gw,
                      const float* __restrict__ gb, const float* __restrict__ gms,
                      float* __restrict__ alpha, float* __restrict__ beta) {
    int c = threadIdx.x;  // 128 threads
    float s = 0.f, q = 0.f;
    for (int b = 0; b < 8; b++) { s += stats[b * 256 + c]; q += stats[b * 256 + 128 + c]; }
    float mean = s * (1.f / NN);
    float ctr = gms[c] * mean;
    float var = q * (1.f / NN) - 2.f * ctr * mean + ctr * ctr;
    float al = gw[c] * rsqrtf(var + EPSV);
    alpha[c] = al;
    beta[c] = gb[c] - al * ctr;
}

// ---------------- GEMM 2 (fused): x1 = x + lrelu(a1*T+b1); H=x1@Wg; a_s,a_d ----------------
__launch_bounds__(256, 4)
__global__ void k_gemm2(const float* __restrict__ X, const float* __restrict__ T,
                        const unsigned short* __restrict__ Wsw, const float* __restrict__ alpha,
                        const float* __restrict__ beta, const float* __restrict__ attS,
                        const float* __restrict__ attD, float* __restrict__ X1out,
                        unsigned short* __restrict__ H, float* __restrict__ a_s, float* __restrict__ a_d) {
    __shared__ __align__(16) short Xl[64 * 136];
    int t = threadIdx.x, wave = t >> 6, lane = t & 63;
    int row0 = blockIdx.x * 64;
    {   // fused staging: x1 = x + lrelu(alpha*T+beta); store fp32 X1out; bf16 -> LDS
        int r = t >> 2, q = t & 3;
        int gr = row0 + r;
        size_t base = (size_t)gr * CH;
#pragma unroll
        for (int j = 0; j < 4; j++) {
            int c0 = q * 32 + j * 8;
            float4 v0 = {0.f,0.f,0.f,0.f}, v1 = {0.f,0.f,0.f,0.f};
            if (gr < NN) {
                float4 xv0 = *(const float4*)&X[base + c0];
                float4 xv1 = *(const float4*)&X[base + c0 + 4];
                float4 tv0 = *(const float4*)&T[base + c0];
                float4 tv1 = *(const float4*)&T[base + c0 + 4];
                float4 al0 = *(const float4*)&alpha[c0];
                float4 al1 = *(const float4*)&alpha[c0 + 4];
                float4 be0 = *(const float4*)&beta[c0];
                float4 be1 = *(const float4*)&beta[c0 + 4];
                v0.x = xv0.x + lrelu(fmaf(al0.x, tv0.x, be0.x), 0.01f);
                v0.y = xv0.y + lrelu(fmaf(al0.y, tv0.y, be0.y), 0.01f);
                v0.z = xv0.z + lrelu(fmaf(al0.z, tv0.z, be0.z), 0.01f);
                v0.w = xv0.w + lrelu(fmaf(al0.w, tv0.w, be0.w), 0.01f);
                v1.x = xv1.x + lrelu(fmaf(al1.x, tv1.x, be1.x), 0.01f);
                v1.y = xv1.y + lrelu(fmaf(al1.y, tv1.y, be1.y), 0.01f);
                v1.z = xv1.z + lrelu(fmaf(al1.z, tv1.z, be1.z), 0.01f);
                v1.w = xv1.w + lrelu(fmaf(al1.w, tv1.w, be1.w), 0.01f);
                *(float4*)&X1out[base + c0] = v0;
                *(float4*)&X1out[base + c0 + 4] = v1;
            }
            short8 s;
            s[0]=f2bf(v0.x); s[1]=f2bf(v0.y); s[2]=f2bf(v0.z); s[3]=f2bf(v0.w);
            s[4]=f2bf(v1.x); s[5]=f2bf(v1.y); s[6]=f2bf(v1.z); s[7]=f2bf(v1.w);
            *(short8*)&Xl[r * 136 + c0] = s;
        }
    }
    __syncthreads();
    floatx4 acc[8];
#pragma unroll
    for (int nt = 0; nt < 8; nt++) acc[nt] = (floatx4){0.f, 0.f, 0.f, 0.f};
    int arow = wave * 16 + (lane & 15);
    int koff = (lane >> 4) * 8;
#pragma unroll
    for (int ks = 0; ks < 4; ks++) {
        short8 af = *(short8*)&Xl[arow * 136 + ks * 32 + koff];
#pragma unroll
        for (int nt = 0; nt < 8; nt++) {
            short8 bf = *(const short8*)&Wsw[((nt * 4 + ks) * 64 + lane) * 8];
            acc[nt] = __builtin_amdgcn_mfma_f32_16x16x32_bf16(af, bf, acc[nt], 0, 0, 0);
        }
    }
    int orow0 = row0 + wave * 16 + (lane >> 4) * 4;
    int ocol = lane & 15;
    float ps[4] = {0.f, 0.f, 0.f, 0.f}, pd[4] = {0.f, 0.f, 0.f, 0.f};
#pragma unroll
    for (int nt = 0; nt < 8; nt++) {
        float as_v = attS[nt * 16 + ocol];
        float ad_v = attD[nt * 16 + ocol];
#pragma unroll
        for (int r = 0; r < 4; r++) {
            int row = orow0 + r;
            if (row < NN) H[(size_t)row * CH + nt * 16 + ocol] = f2bf(acc[nt][r]);
            ps[r] = fmaf(acc[nt][r], as_v, ps[r]);
            pd[r] = fmaf(acc[nt][r], ad_v, pd[r]);
        }
    }
#pragma unroll
    for (int off = 1; off < 16; off <<= 1) {
#pragma unroll
        for (int r = 0; r < 4; r++) {
            ps[r] += __shfl_xor(ps[r], off);
            pd[r] += __shfl_xor(pd[r], off);
        }
    }
    if ((lane & 15) == 0) {
#pragma unroll
        for (int r = 0; r < 4; r++) {
            int row = orow0 + r;
            if (row < NN) { a_s[row] = ps[r]; a_d[row] = pd[r]; }
        }
    }
}

// ---------------- GAT aggregation (softmax over in-edges) + bias + stats (bf16 H) ----------------
__launch_bounds__(256)
__global__ void k_gat_agg(const unsigned short* __restrict__ H, const int* __restrict__ csr,
                          const int* __restrict__ rowptr, const float* __restrict__ a_s,
                          const float* __restrict__ a_d, const float* __restrict__ bg,
                          float* __restrict__ T, float* __restrict__ stats) {
    int t = threadIdx.x, wave = t >> 6, lane = t & 63;
    float2 bias = *(const float2*)&bg[lane * 2];
    float2 ssum = {0.f, 0.f}, ssq = {0.f, 0.f};
    for (int node = blockIdx.x * 4 + wave; node < NN; node += gridDim.x * 4) {
        int beg = rowptr[node], end = rowptr[node + 1];
        float adI = a_d[node];
        float m = -1e30f;
        for (int k = beg + lane; k < end; k += 64) {
            float e = lrelu(a_s[csr[k]] + adI, 0.2f);
            m = fmaxf(m, e);
        }
        for (int off = 32; off > 0; off >>= 1) m = fmaxf(m, __shfl_xor(m, off));
        float den = 0.f;
        float2 acc = {0.f, 0.f};
        for (int k = beg; k < end; k++) {
            int s = csr[k];
            float e = lrelu(a_s[s] + adI, 0.2f);
            float wgt = __expf(e - m);
            den += wgt;
            unsigned int u = *(const unsigned int*)&H[(size_t)s * CH + lane * 2];
            float hx = __uint_as_float(u << 16);
            float hy = __uint_as_float(u & 0xFFFF0000u);
            acc.x = fmaf(wgt, hx, acc.x); acc.y = fmaf(wgt, hy, acc.y);
        }
        float inv = 1.f / den;
        float2 tv = {fmaf(acc.x, inv, bias.x), fmaf(acc.y, inv, bias.y)};
        *(float2*)&T[(size_t)node * CH + lane * 2] = tv;
        ssum.x += tv.x; ssum.y += tv.y;
        ssq.x = fmaf(tv.x, tv.x, ssq.x); ssq.y = fmaf(tv.y, tv.y, ssq.y);
    }
    __shared__ float red[4][64][4];
    red[wave][lane][0] = ssum.x; red[wave][lane][1] = ssum.y;
    red[wave][lane][2] = ssq.x;  red[wave][lane][3] = ssq.y;
    __syncthreads();
    if (wave == 0) {
        float v0 = 0.f, v1 = 0.f, v2 = 0.f, v3 = 0.f;
        for (int w2 = 0; w2 < 4; w2++) {
            v0 += red[w2][lane][0]; v1 += red[w2][lane][1];
            v2 += red[w2][lane][2]; v3 += red[w2][lane][3];
        }
        float* bank = stats + (blockIdx.x & 7) * 256;
        atomicAdd(&bank[2 * lane], v0);
        atomicAdd(&bank[2 * lane + 1], v1);
        atomicAdd(&bank[128 + 2 * lane], v2);
        atomicAdd(&bank[128 + 2 * lane + 1], v3);
    }
}

// ---------------- final: out = x1 + lrelu(a2*T2+b2) ----------------
__global__ void k_final(const float* __restrict__ T, const float* __restrict__ alpha,
                        const float* __restrict__ beta, float* __restrict__ out) {
    size_t i = (size_t)(blockIdx.x * 256 + threadIdx.x) * 4;
    if (i >= (size_t)NN * CH) return;
    int c = (int)(i & (CH - 1));
    float4 tv = *(const float4*)&T[i];
    float4 av = *(const float4*)&alpha[c];
    float4 bv = *(const float4*)&beta[c];
    float4 o = *(float4*)&out[i];
    o.x += lrelu(fmaf(av.x, tv.x, bv.x), 0.01f);
    o.y += lrelu(fmaf(av.y, tv.y, bv.y), 0.01f);
    o.z += lrelu(fmaf(av.z, tv.z, bv.z), 0.01f);
    o.w += lrelu(fmaf(av.w, tv.w, bv.w), 0.01f);
    *(float4*)&out[i] = o;
}

extern "C" void kernel_launch(void* const* d_in, const int* in_sizes, int n_in,
                              void* d_out, int out_size, void* d_ws, size_t ws_size,
                              hipStream_t stream) {
    const float* x    = (const float*)d_in[0];
    const int*   edges= (const int*)d_in[1];
    const float* W1   = (const float*)d_in[2];
    const float* b1   = (const float*)d_in[3];
    const float* gw   = (const float*)d_in[4];
    const float* gb   = (const float*)d_in[5];
    const float* gms  = (const float*)d_in[6];
    const float* Wg   = (const float*)d_in[7];
    const float* bg   = (const float*)d_in[8];
    const float* attS = (const float*)d_in[9];
    const float* attD = (const float*)d_in[10];
    float* out = (float*)d_out;

    char* w = (char*)d_ws;
    size_t o = 0;
    unsigned short* H = (unsigned short*)(w + o); o += (size_t)NN * CH * 2;  // 25.6 MB bf16
    float* T      = (float*)(w + o); o += (size_t)NN * CH * 4;               // 51.2 MB
    int*   csr    = (int*)(w + o);   o += (size_t)TOTE * 4;                  // 6.8 MB
    int*   rowptr = (int*)(w + o);   o += (size_t)(NN + 64) * 4;
    int*   deg    = (int*)(w + o);   o += (size_t)NN * 4;
    int*   cursor = (int*)(w + o);   o += (size_t)NN * 4;
    float* dinv   = (float*)(w + o); o += (size_t)NN * 4;
    float* a_s    = (float*)(w + o); o += (size_t)NN * 4;
    float* a_d    = (float*)(w + o); o += (size_t)NN * 4;
    int*   bsum   = (int*)(w + o);   o += 512;
    int*   boff   = (int*)(w + o);   o += 512;
    float* stats  = (float*)(w + o); o += 4096 * 4;
    float* alpha1 = (float*)(w + o); o += 512;
    float* beta1  = (float*)(w + o); o += 512;
    float* alpha2 = (float*)(w + o); o += 512;
    float* beta2  = (float*)(w + o); o += 512;
    unsigned short* Wsw1 = (unsigned short*)(w + o); o += 16384 * 2;
    unsigned short* Wsw2 = (unsigned short*)(w + o); o += 16384 * 2;

    k_init <<<(NN + 255) / 256, 256, 0, stream>>>(deg, cursor, stats);
    k_count<<<(NE + 255) / 256, 256, 0, stream>>>(edges, deg);
    k_scan1<<<NB, 256, 0, stream>>>(deg, bsum, dinv);
    k_scan2<<<1, 32, 0, stream>>>(bsum, boff);
    k_scan3<<<NB, 256, 0, stream>>>(deg, boff, rowptr);
    k_fill <<<(TOTE + 255) / 256, 256, 0, stream>>>(edges, rowptr, cursor, csr);
    k_wswz <<<64, 256, 0, stream>>>(W1, Wg, Wsw1, Wsw2);

    k_gemm1  <<<NGB, 256, 0, stream>>>(x, Wsw1, H);
    k_gcn_agg<<<2048, 256, 0, stream>>>(H, csr, rowptr, dinv, b1, T, stats);
    k_fin    <<<1, 128, 0, stream>>>(stats, gw, gb, gms, alpha1, beta1);

    k_gemm2  <<<NGB, 256, 0, stream>>>(x, T, Wsw2, alpha1, beta1, attS, attD, out, H, a_s, a_d);
    k_gat_agg<<<2048, 256, 0, stream>>>(H, csr, rowptr, a_s, a_d, bg, T, stats + 2048);
    k_fin    <<<1, 128, 0, stream>>>(stats + 2048, gw, gb, gms, alpha2, beta2);

    k_final<<<(NN * CH / 4 + 255) / 256, 256, 0, stream>>>(T, alpha2, beta2, out);
}

// Round 4
// 525.249 us; speedup vs baseline: 1.9623x; 1.3658x over previous
//
#include <hip/hip_runtime.h>
#include <math.h>

#define NN 100000
#define NE 1600000
#define CH 128
#define TOTE (NE + NN)
#define EPSV 1e-5f
#define NB 98    // ceil(NN/1024)
#define NGB 1563 // ceil(NN/64)

typedef __attribute__((ext_vector_type(8))) short short8;
typedef __attribute__((ext_vector_type(4))) float floatx4;

__device__ __forceinline__ float lrelu(float v, float s) { return v < 0.f ? v * s : v; }

__device__ __forceinline__ unsigned short f2bf(float f) {
    unsigned int u = __float_as_uint(f);
    u += 0x7FFF + ((u >> 16) & 1);   // round-to-nearest-even
    return (unsigned short)(u >> 16);
}
__device__ __forceinline__ float bflo(unsigned int u) { return __uint_as_float(u << 16); }
__device__ __forceinline__ float bfhi(unsigned int u) { return __uint_as_float(u & 0xFFFF0000u); }

// ---------------- CSR build ----------------
__global__ void k_init(int* __restrict__ deg, int* __restrict__ cursor, float* __restrict__ stats) {
    int i = blockIdx.x * 256 + threadIdx.x;
    if (i < NN) { deg[i] = 1; cursor[i] = 0; }   // deg=1 accounts for the self-loop
    if (i < 4096) stats[i] = 0.f;
}

__global__ void k_count(const int* __restrict__ edges, int* __restrict__ deg) {
    int i = blockIdx.x * 256 + threadIdx.x;
    if (i < NE) atomicAdd(&deg[edges[NE + i]], 1);
}

__global__ void k_scan1(const int* __restrict__ deg, int* __restrict__ bsum, float* __restrict__ dinv) {
    __shared__ int red[256];
    int t = threadIdx.x;
    int base = blockIdx.x * 1024 + t * 4;
    int s = 0;
#pragma unroll
    for (int j = 0; j < 4; j++) {
        int i = base + j;
        if (i < NN) { int d = deg[i]; s += d; dinv[i] = rsqrtf((float)d); }
    }
    red[t] = s; __syncthreads();
    for (int off = 128; off > 0; off >>= 1) { if (t < off) red[t] += red[t + off]; __syncthreads(); }
    if (t == 0) bsum[blockIdx.x] = red[0];
}

__global__ void k_scan2(const int* __restrict__ bsum, int* __restrict__ boff) {
    if (threadIdx.x == 0) {
        int acc = 0;
        for (int b = 0; b < NB; b++) { boff[b] = acc; acc += bsum[b]; }
    }
}

__global__ void k_scan3(const int* __restrict__ deg, const int* __restrict__ boff, int* __restrict__ rowptr) {
    __shared__ int sc[256];
    int t = threadIdx.x;
    int base = blockIdx.x * 1024 + t * 4;
    int d[4];
#pragma unroll
    for (int j = 0; j < 4; j++) { int i = base + j; d[j] = (i < NN) ? deg[i] : 0; }
    int local = d[0] + d[1] + d[2] + d[3];
    sc[t] = local; __syncthreads();
    for (int off = 1; off < 256; off <<= 1) {
        int v = (t >= off) ? sc[t - off] : 0;
        __syncthreads();
        sc[t] += v;
        __syncthreads();
    }
    int run = sc[t] - local + boff[blockIdx.x];
#pragma unroll
    for (int j = 0; j < 4; j++) {
        int i = base + j;
        if (i < NN) { rowptr[i] = run; run += d[j]; }
    }
    if (blockIdx.x == 0 && t == 0) rowptr[NN] = TOTE;
}

__global__ void k_fill(const int* __restrict__ edges, const int* __restrict__ rowptr,
                       int* __restrict__ cursor, int* __restrict__ csr) {
    int i = blockIdx.x * 256 + threadIdx.x;
    if (i < NE) {
        int s = edges[i], d = edges[NE + i];
        int pos = atomicAdd(&cursor[d], 1);
        csr[rowptr[d] + pos] = s;
    } else if (i < TOTE) {
        int v = i - NE;
        int pos = atomicAdd(&cursor[v], 1);
        csr[rowptr[v] + pos] = v;   // self-loop
    }
}

// ---------------- W swizzle into MFMA B-fragment order (bf16) ----------------
__global__ void k_wswz(const float* __restrict__ W1, const float* __restrict__ Wg,
                       unsigned short* __restrict__ Wsw1, unsigned short* __restrict__ Wsw2) {
    int t = blockIdx.x * 256 + threadIdx.x;
    if (t >= 16384) return;
    int j = t & 7, lane = (t >> 3) & 63, ks = (t >> 9) & 3, nt = t >> 11;
    int k = ks * 32 + (lane >> 4) * 8 + j;
    int n = nt * 16 + (lane & 15);
    Wsw1[t] = f2bf(W1[k * CH + n]);
    Wsw2[t] = f2bf(Wg[k * CH + n]);
}

// ---------------- GEMM 1: H(bf16) = X @ W1 via MFMA ----------------
__launch_bounds__(256, 4)
__global__ void k_gemm1(const float* __restrict__ X, const unsigned short* __restrict__ Wsw,
                        unsigned short* __restrict__ H) {
    __shared__ __align__(16) short Xl[64 * 136];
    int t = threadIdx.x, wave = t >> 6, lane = t & 63;
    int row0 = blockIdx.x * 64;
    {   // stage X tile -> bf16 LDS
        int r = t >> 2, q = t & 3;
        int gr = row0 + r;
        const float* Xr = X + (size_t)gr * CH;
#pragma unroll
        for (int j = 0; j < 4; j++) {
            int c0 = q * 32 + j * 8;
            float4 v0 = {0.f,0.f,0.f,0.f}, v1 = {0.f,0.f,0.f,0.f};
            if (gr < NN) { v0 = *(const float4*)&Xr[c0]; v1 = *(const float4*)&Xr[c0 + 4]; }
            short8 s;
            s[0]=f2bf(v0.x); s[1]=f2bf(v0.y); s[2]=f2bf(v0.z); s[3]=f2bf(v0.w);
            s[4]=f2bf(v1.x); s[5]=f2bf(v1.y); s[6]=f2bf(v1.z); s[7]=f2bf(v1.w);
            *(short8*)&Xl[r * 136 + c0] = s;
        }
    }
    __syncthreads();
    floatx4 acc[8];
#pragma unroll
    for (int nt = 0; nt < 8; nt++) acc[nt] = (floatx4){0.f, 0.f, 0.f, 0.f};
    int arow = wave * 16 + (lane & 15);
    int koff = (lane >> 4) * 8;
#pragma unroll
    for (int ks = 0; ks < 4; ks++) {
        short8 af = *(short8*)&Xl[arow * 136 + ks * 32 + koff];
#pragma unroll
        for (int nt = 0; nt < 8; nt++) {
            short8 bf = *(const short8*)&Wsw[((nt * 4 + ks) * 64 + lane) * 8];
            acc[nt] = __builtin_amdgcn_mfma_f32_16x16x32_bf16(af, bf, acc[nt], 0, 0, 0);
        }
    }
    int orow0 = row0 + wave * 16 + (lane >> 4) * 4;
    int ocol = lane & 15;
#pragma unroll
    for (int nt = 0; nt < 8; nt++) {
#pragma unroll
        for (int r = 0; r < 4; r++) {
            int row = orow0 + r;
            if (row < NN) H[(size_t)row * CH + nt * 16 + ocol] = f2bf(acc[nt][r]);
        }
    }
}

// ---------------- GCN aggregation: 4 edges/iter, 16-lane row slices, prefetch ----------------
__launch_bounds__(256)
__global__ void k_gcn_agg(const unsigned short* __restrict__ H, const int* __restrict__ csr,
                          const int* __restrict__ rowptr, const float* __restrict__ dinv,
                          const float* __restrict__ b1, unsigned short* __restrict__ T,
                          float* __restrict__ stats) {
    __shared__ float red_s[4][128], red_q[4][128];
    int t = threadIdx.x, wave = t >> 6, lane = t & 63;
    int g = lane >> 4, sl = lane & 15;
    float4 bb0 = *(const float4*)&b1[sl * 8];
    float4 bb1 = *(const float4*)&b1[sl * 8 + 4];
    float bias[8] = {bb0.x, bb0.y, bb0.z, bb0.w, bb1.x, bb1.y, bb1.z, bb1.w};
    float ssum[8], ssq[8];
#pragma unroll
    for (int j = 0; j < 8; j++) { ssum[j] = 0.f; ssq[j] = 0.f; }
    for (int node = blockIdx.x * 4 + wave; node < NN; node += gridDim.x * 4) {
        int beg = rowptr[node], end = rowptr[node + 1];
        float di = dinv[node];
        float acc[8];
#pragma unroll
        for (int j = 0; j < 8; j++) acc[j] = 0.f;
        int kk0 = beg + g;
        int s_cur = csr[kk0 < end ? kk0 : end - 1];
        for (int k = beg; k < end; k += 4) {
            int kn = k + 4 + g;
            int s_next = csr[kn < end ? kn : end - 1];
            bool valid = (k + g) < end;
            float w = valid ? dinv[s_cur] : 0.f;
            uint4 u = *(const uint4*)&H[(size_t)s_cur * CH + sl * 8];
            acc[0] = fmaf(w, bflo(u.x), acc[0]); acc[1] = fmaf(w, bfhi(u.x), acc[1]);
            acc[2] = fmaf(w, bflo(u.y), acc[2]); acc[3] = fmaf(w, bfhi(u.y), acc[3]);
            acc[4] = fmaf(w, bflo(u.z), acc[4]); acc[5] = fmaf(w, bfhi(u.z), acc[5]);
            acc[6] = fmaf(w, bflo(u.w), acc[6]); acc[7] = fmaf(w, bfhi(u.w), acc[7]);
            s_cur = s_next;
        }
#pragma unroll
        for (int j = 0; j < 8; j++) {
            acc[j] += __shfl_xor(acc[j], 16);
            acc[j] += __shfl_xor(acc[j], 32);
        }
        if (lane < 16) {
            short8 sv;
#pragma unroll
            for (int j = 0; j < 8; j++) {
                float tv = fmaf(di, acc[j], bias[j]);
                sv[j] = (short)f2bf(tv);
                ssum[j] += tv; ssq[j] = fmaf(tv, tv, ssq[j]);
            }
            *(short8*)&T[(size_t)node * CH + sl * 8] = sv;
        }
    }
    if (lane < 16) {
#pragma unroll
        for (int j = 0; j < 8; j++) { red_s[wave][sl * 8 + j] = ssum[j]; red_q[wave][sl * 8 + j] = ssq[j]; }
    }
    __syncthreads();
    if (t < 128) {
        float s = 0.f, q = 0.f;
        for (int w2 = 0; w2 < 4; w2++) { s += red_s[w2][t]; q += red_q[w2][t]; }
        float* bank = stats + (blockIdx.x & 7) * 256;
        atomicAdd(&bank[t], s);
        atomicAdd(&bank[128 + t], q);
    }
}

// ---------------- GraphNorm finalize ----------------
__global__ void k_fin(const float* __restrict__ stats, const float* __restrict__ gw,
                      const float* __restrict__ gb, const float* __restrict__ gms,
                      float* __restrict__ alpha, float* __restrict__ beta) {
    int c = threadIdx.x;  // 128 threads
    float s = 0.f, q = 0.f;
    for (int b = 0; b < 8; b++) { s += stats[b * 256 + c]; q += stats[b * 256 + 128 + c]; }
    float mean = s * (1.f / NN);
    float ctr = gms[c] * mean;
    float var = q * (1.f / NN) - 2.f * ctr * mean + ctr * ctr;
    float al = gw[c] * rsqrtf(var + EPSV);
    alpha[c] = al;
    beta[c] = gb[c] - al * ctr;
}

// ---------------- GEMM 2 (fused): x1 = x + lrelu(a1*T+b1); H=x1@Wg; a_s,a_d ----------------
__launch_bounds__(256, 4)
__global__ void k_gemm2(const float* __restrict__ X, const unsigned short* __restrict__ T,
                        const unsigned short* __restrict__ Wsw, const float* __restrict__ alpha,
                        const float* __restrict__ beta, const float* __restrict__ attS,
                        const float* __restrict__ attD, float* __restrict__ X1out,
                        unsigned short* __restrict__ H, float* __restrict__ a_s, float* __restrict__ a_d) {
    __shared__ __align__(16) short Xl[64 * 136];
    int t = threadIdx.x, wave = t >> 6, lane = t & 63;
    int row0 = blockIdx.x * 64;
    {   // fused staging: x1 = x + lrelu(alpha*T+beta); store fp32 X1out; bf16 -> LDS
        int r = t >> 2, q = t & 3;
        int gr = row0 + r;
        size_t base = (size_t)gr * CH;
#pragma unroll
        for (int j = 0; j < 4; j++) {
            int c0 = q * 32 + j * 8;
            float4 v0 = {0.f,0.f,0.f,0.f}, v1 = {0.f,0.f,0.f,0.f};
            if (gr < NN) {
                float4 xv0 = *(const float4*)&X[base + c0];
                float4 xv1 = *(const float4*)&X[base + c0 + 4];
                uint4 tu = *(const uint4*)&T[base + c0];
                float4 al0 = *(const float4*)&alpha[c0];
                float4 al1 = *(const float4*)&alpha[c0 + 4];
                float4 be0 = *(const float4*)&beta[c0];
                float4 be1 = *(const float4*)&beta[c0 + 4];
                v0.x = xv0.x + lrelu(fmaf(al0.x, bflo(tu.x), be0.x), 0.01f);
                v0.y = xv0.y + lrelu(fmaf(al0.y, bfhi(tu.x), be0.y), 0.01f);
                v0.z = xv0.z + lrelu(fmaf(al0.z, bflo(tu.y), be0.z), 0.01f);
                v0.w = xv0.w + lrelu(fmaf(al0.w, bfhi(tu.y), be0.w), 0.01f);
                v1.x = xv1.x + lrelu(fmaf(al1.x, bflo(tu.z), be1.x), 0.01f);
                v1.y = xv1.y + lrelu(fmaf(al1.y, bfhi(tu.z), be1.y), 0.01f);
                v1.z = xv1.z + lrelu(fmaf(al1.z, bflo(tu.w), be1.z), 0.01f);
                v1.w = xv1.w + lrelu(fmaf(al1.w, bfhi(tu.w), be1.w), 0.01f);
                *(float4*)&X1out[base + c0] = v0;
                *(float4*)&X1out[base + c0 + 4] = v1;
            }
            short8 s;
            s[0]=f2bf(v0.x); s[1]=f2bf(v0.y); s[2]=f2bf(v0.z); s[3]=f2bf(v0.w);
            s[4]=f2bf(v1.x); s[5]=f2bf(v1.y); s[6]=f2bf(v1.z); s[7]=f2bf(v1.w);
            *(short8*)&Xl[r * 136 + c0] = s;
        }
    }
    __syncthreads();
    floatx4 acc[8];
#pragma unroll
    for (int nt = 0; nt < 8; nt++) acc[nt] = (floatx4){0.f, 0.f, 0.f, 0.f};
    int arow = wave * 16 + (lane & 15);
    int koff = (lane >> 4) * 8;
#pragma unroll
    for (int ks = 0; ks < 4; ks++) {
        short8 af = *(short8*)&Xl[arow * 136 + ks * 32 + koff];
#pragma unroll
        for (int nt = 0; nt < 8; nt++) {
            short8 bf = *(const short8*)&Wsw[((nt * 4 + ks) * 64 + lane) * 8];
            acc[nt] = __builtin_amdgcn_mfma_f32_16x16x32_bf16(af, bf, acc[nt], 0, 0, 0);
        }
    }
    int orow0 = row0 + wave * 16 + (lane >> 4) * 4;
    int ocol = lane & 15;
    float ps[4] = {0.f, 0.f, 0.f, 0.f}, pd[4] = {0.f, 0.f, 0.f, 0.f};
#pragma unroll
    for (int nt = 0; nt < 8; nt++) {
        float as_v = attS[nt * 16 + ocol];
        float ad_v = attD[nt * 16 + ocol];
#pragma unroll
        for (int r = 0; r < 4; r++) {
            int row = orow0 + r;
            if (row < NN) H[(size_t)row * CH + nt * 16 + ocol] = f2bf(acc[nt][r]);
            ps[r] = fmaf(acc[nt][r], as_v, ps[r]);
            pd[r] = fmaf(acc[nt][r], ad_v, pd[r]);
        }
    }
#pragma unroll
    for (int off = 1; off < 16; off <<= 1) {
#pragma unroll
        for (int r = 0; r < 4; r++) {
            ps[r] += __shfl_xor(ps[r], off);
            pd[r] += __shfl_xor(pd[r], off);
        }
    }
    if ((lane & 15) == 0) {
#pragma unroll
        for (int r = 0; r < 4; r++) {
            int row = orow0 + r;
            if (row < NN) { a_s[row] = ps[r]; a_d[row] = pd[r]; }
        }
    }
}

// ---------------- GAT aggregation: single-pass softmax (no max needed; |e|<~10) ----------------
__launch_bounds__(256)
__global__ void k_gat_agg(const unsigned short* __restrict__ H, const int* __restrict__ csr,
                          const int* __restrict__ rowptr, const float* __restrict__ a_s,
                          const float* __restrict__ a_d, const float* __restrict__ bg,
                          unsigned short* __restrict__ T, float* __restrict__ stats) {
    __shared__ float red_s[4][128], red_q[4][128];
    int t = threadIdx.x, wave = t >> 6, lane = t & 63;
    int g = lane >> 4, sl = lane & 15;
    float4 bb0 = *(const float4*)&bg[sl * 8];
    float4 bb1 = *(const float4*)&bg[sl * 8 + 4];
    float bias[8] = {bb0.x, bb0.y, bb0.z, bb0.w, bb1.x, bb1.y, bb1.z, bb1.w};
    float ssum[8], ssq[8];
#pragma unroll
    for (int j = 0; j < 8; j++) { ssum[j] = 0.f; ssq[j] = 0.f; }
    for (int node = blockIdx.x * 4 + wave; node < NN; node += gridDim.x * 4) {
        int beg = rowptr[node], end = rowptr[node + 1];
        float adI = a_d[node];
        float acc[8];
#pragma unroll
        for (int j = 0; j < 8; j++) acc[j] = 0.f;
        float den = 0.f;
        int kk0 = beg + g;
        int s_cur = csr[kk0 < end ? kk0 : end - 1];
        for (int k = beg; k < end; k += 4) {
            int kn = k + 4 + g;
            int s_next = csr[kn < end ? kn : end - 1];
            bool valid = (k + g) < end;
            float e = lrelu(a_s[s_cur] + adI, 0.2f);
            float wgt = valid ? __expf(e) : 0.f;
            den += wgt;
            uint4 u = *(const uint4*)&H[(size_t)s_cur * CH + sl * 8];
            acc[0] = fmaf(wgt, bflo(u.x), acc[0]); acc[1] = fmaf(wgt, bfhi(u.x), acc[1]);
            acc[2] = fmaf(wgt, bflo(u.y), acc[2]); acc[3] = fmaf(wgt, bfhi(u.y), acc[3]);
            acc[4] = fmaf(wgt, bflo(u.z), acc[4]); acc[5] = fmaf(wgt, bfhi(u.z), acc[5]);
            acc[6] = fmaf(wgt, bflo(u.w), acc[6]); acc[7] = fmaf(wgt, bfhi(u.w), acc[7]);
            s_cur = s_next;
        }
#pragma unroll
        for (int j = 0; j < 8; j++) {
            acc[j] += __shfl_xor(acc[j], 16);
            acc[j] += __shfl_xor(acc[j], 32);
        }
        den += __shfl_xor(den, 16);
        den += __shfl_xor(den, 32);
        float inv = 1.f / den;
        if (lane < 16) {
            short8 sv;
#pragma unroll
            for (int j = 0; j < 8; j++) {
                float tv = fmaf(acc[j], inv, bias[j]);
                sv[j] = (short)f2bf(tv);
                ssum[j] += tv; ssq[j] = fmaf(tv, tv, ssq[j]);
            }
            *(short8*)&T[(size_t)node * CH + sl * 8] = sv;
        }
    }
    if (lane < 16) {
#pragma unroll
        for (int j = 0; j < 8; j++) { red_s[wave][sl * 8 + j] = ssum[j]; red_q[wave][sl * 8 + j] = ssq[j]; }
    }
    __syncthreads();
    if (t < 128) {
        float s = 0.f, q = 0.f;
        for (int w2 = 0; w2 < 4; w2++) { s += red_s[w2][t]; q += red_q[w2][t]; }
        float* bank = stats + (blockIdx.x & 7) * 256;
        atomicAdd(&bank[t], s);
        atomicAdd(&bank[128 + t], q);
    }
}

// ---------------- final: out = x1 + lrelu(a2*T2+b2)  (T2 bf16) ----------------
__global__ void k_final(const unsigned short* __restrict__ T, const float* __restrict__ alpha,
                        const float* __restrict__ beta, float* __restrict__ out) {
    size_t i = (size_t)(blockIdx.x * 256 + threadIdx.x) * 4;
    if (i >= (size_t)NN * CH) return;
    int c = (int)(i & (CH - 1));
    uint2 tu = *(const uint2*)&T[i];
    float4 av = *(const float4*)&alpha[c];
    float4 bv = *(const float4*)&beta[c];
    float4 o = *(float4*)&out[i];
    o.x += lrelu(fmaf(av.x, bflo(tu.x), bv.x), 0.01f);
    o.y += lrelu(fmaf(av.y, bfhi(tu.x), bv.y), 0.01f);
    o.z += lrelu(fmaf(av.z, bflo(tu.y), bv.z), 0.01f);
    o.w += lrelu(fmaf(av.w, bfhi(tu.y), bv.w), 0.01f);
    *(float4*)&out[i] = o;
}

extern "C" void kernel_launch(void* const* d_in, const int* in_sizes, int n_in,
                              void* d_out, int out_size, void* d_ws, size_t ws_size,
                              hipStream_t stream) {
    const float* x    = (const float*)d_in[0];
    const int*   edges= (const int*)d_in[1];
    const float* W1   = (const float*)d_in[2];
    const float* b1   = (const float*)d_in[3];
    const float* gw   = (const float*)d_in[4];
    const float* gb   = (const float*)d_in[5];
    const float* gms  = (const float*)d_in[6];
    const float* Wg   = (const float*)d_in[7];
    const float* bg   = (const float*)d_in[8];
    const float* attS = (const float*)d_in[9];
    const float* attD = (const float*)d_in[10];
    float* out = (float*)d_out;

    char* w = (char*)d_ws;
    size_t o = 0;
    unsigned short* H = (unsigned short*)(w + o); o += (size_t)NN * CH * 2;  // 25.6 MB bf16
    unsigned short* T = (unsigned short*)(w + o); o += (size_t)NN * CH * 2;  // 25.6 MB bf16
    int*   csr    = (int*)(w + o);   o += (size_t)TOTE * 4;                  // 6.8 MB
    int*   rowptr = (int*)(w + o);   o += (size_t)(NN + 64) * 4;
    int*   deg    = (int*)(w + o);   o += (size_t)NN * 4;
    int*   cursor = (int*)(w + o);   o += (size_t)NN * 4;
    float* dinv   = (float*)(w + o); o += (size_t)NN * 4;
    float* a_s    = (float*)(w + o); o += (size_t)NN * 4;
    float* a_d    = (float*)(w + o); o += (size_t)NN * 4;
    int*   bsum   = (int*)(w + o);   o += 512;
    int*   boff   = (int*)(w + o);   o += 512;
    float* stats  = (float*)(w + o); o += 4096 * 4;
    float* alpha1 = (float*)(w + o); o += 512;
    float* beta1  = (float*)(w + o); o += 512;
    float* alpha2 = (float*)(w + o); o += 512;
    float* beta2  = (float*)(w + o); o += 512;
    unsigned short* Wsw1 = (unsigned short*)(w + o); o += 16384 * 2;
    unsigned short* Wsw2 = (unsigned short*)(w + o); o += 16384 * 2;

    k_init <<<(NN + 255) / 256, 256, 0, stream>>>(deg, cursor, stats);
    k_count<<<(NE + 255) / 256, 256, 0, stream>>>(edges, deg);
    k_scan1<<<NB, 256, 0, stream>>>(deg, bsum, dinv);
    k_scan2<<<1, 32, 0, stream>>>(bsum, boff);
    k_scan3<<<NB, 256, 0, stream>>>(deg, boff, rowptr);
    k_fill <<<(TOTE + 255) / 256, 256, 0, stream>>>(edges, rowptr, cursor, csr);
    k_wswz <<<64, 256, 0, stream>>>(W1, Wg, Wsw1, Wsw2);

    k_gemm1  <<<NGB, 256, 0, stream>>>(x, Wsw1, H);
    k_gcn_agg<<<2048, 256, 0, stream>>>(H, csr, rowptr, dinv, b1, T, stats);
    k_fin    <<<1, 128, 0, stream>>>(stats, gw, gb, gms, alpha1, beta1);

    k_gemm2  <<<NGB, 256, 0, stream>>>(x, T, Wsw2, alpha1, beta1, attS, attD, out, H, a_s, a_d);
    k_gat_agg<<<2048, 256, 0, stream>>>(H, csr, rowptr, a_s, a_d, bg, T, stats + 2048);
    k_fin    <<<1, 128, 0, stream>>>(stats + 2048, gw, gb, gms, alpha2, beta2);

    k_final<<<(NN * CH / 4 + 255) / 256, 256, 0, stream>>>(T, alpha2, beta2, out);
}

// Round 5
// 510.858 us; speedup vs baseline: 2.0176x; 1.0282x over previous
//
#include <hip/hip_runtime.h>
#include <math.h>

#define NN 100000
#define NE 1600000
#define CH 128
#define TOTE (NE + NN)
#define EPSV 1e-5f
#define NB 98    // ceil(NN/1024)
#define NGB 1563 // ceil(NN/64)

typedef __attribute__((ext_vector_type(8))) short short8;
typedef __attribute__((ext_vector_type(4))) float floatx4;

__device__ __forceinline__ float lrelu(float v, float s) { return v < 0.f ? v * s : v; }

__device__ __forceinline__ unsigned short f2bf(float f) {
    unsigned int u = __float_as_uint(f);
    u += 0x7FFF + ((u >> 16) & 1);   // round-to-nearest-even
    return (unsigned short)(u >> 16);
}
__device__ __forceinline__ float bflo(unsigned int u) { return __uint_as_float(u << 16); }
__device__ __forceinline__ float bfhi(unsigned int u) { return __uint_as_float(u & 0xFFFF0000u); }

// ---------------- CSR build ----------------
__global__ void k_init(int* __restrict__ deg, int* __restrict__ cursor, float* __restrict__ stats) {
    int i = blockIdx.x * 256 + threadIdx.x;
    if (i < NN) { deg[i] = 1; cursor[i] = 0; }   // deg=1 accounts for the self-loop
    if (i < 4096) stats[i] = 0.f;
}

__global__ void k_count(const int* __restrict__ edges, int* __restrict__ deg) {
    int i = blockIdx.x * 256 + threadIdx.x;
    if (i < NE) {
        int d = __builtin_nontemporal_load(&edges[NE + i]);
        atomicAdd(&deg[d], 1);
    }
}

__global__ void k_scan1(const int* __restrict__ deg, int* __restrict__ bsum, float* __restrict__ dinv) {
    __shared__ int red[256];
    int t = threadIdx.x;
    int base = blockIdx.x * 1024 + t * 4;
    int s = 0;
#pragma unroll
    for (int j = 0; j < 4; j++) {
        int i = base + j;
        if (i < NN) { int d = deg[i]; s += d; dinv[i] = rsqrtf((float)d); }
    }
    red[t] = s; __syncthreads();
    for (int off = 128; off > 0; off >>= 1) { if (t < off) red[t] += red[t + off]; __syncthreads(); }
    if (t == 0) bsum[blockIdx.x] = red[0];
}

__global__ void k_scan2(const int* __restrict__ bsum, int* __restrict__ boff) {
    if (threadIdx.x == 0) {
        int acc = 0;
        for (int b = 0; b < NB; b++) { boff[b] = acc; acc += bsum[b]; }
    }
}

__global__ void k_scan3(const int* __restrict__ deg, const int* __restrict__ boff, int* __restrict__ rowptr) {
    __shared__ int sc[256];
    int t = threadIdx.x;
    int base = blockIdx.x * 1024 + t * 4;
    int d[4];
#pragma unroll
    for (int j = 0; j < 4; j++) { int i = base + j; d[j] = (i < NN) ? deg[i] : 0; }
    int local = d[0] + d[1] + d[2] + d[3];
    sc[t] = local; __syncthreads();
    for (int off = 1; off < 256; off <<= 1) {
        int v = (t >= off) ? sc[t - off] : 0;
        __syncthreads();
        sc[t] += v;
        __syncthreads();
    }
    int run = sc[t] - local + boff[blockIdx.x];
#pragma unroll
    for (int j = 0; j < 4; j++) {
        int i = base + j;
        if (i < NN) { rowptr[i] = run; run += d[j]; }
    }
    if (blockIdx.x == 0 && t == 0) rowptr[NN] = TOTE;
}

// Two dst-range passes: active csr window 3.4 MB < 4 MiB per-XCD L2, so scatter
// lines stay resident until full; nontemporal edge reads avoid evicting them.
__global__ void k_fill(const int* __restrict__ edges, const int* __restrict__ rowptr,
                       int* __restrict__ cursor, int* __restrict__ csr, int lo, int hi) {
    int i = blockIdx.x * 256 + threadIdx.x;
    if (i < NE) {
        int d = __builtin_nontemporal_load(&edges[NE + i]);
        if (d < lo || d >= hi) return;
        int s = __builtin_nontemporal_load(&edges[i]);
        int pos = atomicAdd(&cursor[d], 1);
        csr[rowptr[d] + pos] = s;
    } else if (i < TOTE) {
        int v = i - NE;
        if (v < lo || v >= hi) return;
        int pos = atomicAdd(&cursor[v], 1);
        csr[rowptr[v] + pos] = v;   // self-loop
    }
}

// ---------------- W swizzle into MFMA B-fragment order (bf16) ----------------
__global__ void k_wswz(const float* __restrict__ W1, const float* __restrict__ Wg,
                       unsigned short* __restrict__ Wsw1, unsigned short* __restrict__ Wsw2) {
    int t = blockIdx.x * 256 + threadIdx.x;
    if (t >= 16384) return;
    int j = t & 7, lane = (t >> 3) & 63, ks = (t >> 9) & 3, nt = t >> 11;
    int k = ks * 32 + (lane >> 4) * 8 + j;
    int n = nt * 16 + (lane & 15);
    Wsw1[t] = f2bf(W1[k * CH + n]);
    Wsw2[t] = f2bf(Wg[k * CH + n]);
}

// ---------------- GEMM 1: H(bf16) = X @ W1 via MFMA ----------------
__launch_bounds__(256, 4)
__global__ void k_gemm1(const float* __restrict__ X, const unsigned short* __restrict__ Wsw,
                        unsigned short* __restrict__ H) {
    __shared__ __align__(16) short Xl[64 * 136];
    int t = threadIdx.x, wave = t >> 6, lane = t & 63;
    int row0 = blockIdx.x * 64;
    {   // stage X tile -> bf16 LDS
        int r = t >> 2, q = t & 3;
        int gr = row0 + r;
        const float* Xr = X + (size_t)gr * CH;
#pragma unroll
        for (int j = 0; j < 4; j++) {
            int c0 = q * 32 + j * 8;
            float4 v0 = {0.f,0.f,0.f,0.f}, v1 = {0.f,0.f,0.f,0.f};
            if (gr < NN) { v0 = *(const float4*)&Xr[c0]; v1 = *(const float4*)&Xr[c0 + 4]; }
            short8 s;
            s[0]=f2bf(v0.x); s[1]=f2bf(v0.y); s[2]=f2bf(v0.z); s[3]=f2bf(v0.w);
            s[4]=f2bf(v1.x); s[5]=f2bf(v1.y); s[6]=f2bf(v1.z); s[7]=f2bf(v1.w);
            *(short8*)&Xl[r * 136 + c0] = s;
        }
    }
    __syncthreads();
    floatx4 acc[8];
#pragma unroll
    for (int nt = 0; nt < 8; nt++) acc[nt] = (floatx4){0.f, 0.f, 0.f, 0.f};
    int arow = wave * 16 + (lane & 15);
    int koff = (lane >> 4) * 8;
#pragma unroll
    for (int ks = 0; ks < 4; ks++) {
        short8 af = *(short8*)&Xl[arow * 136 + ks * 32 + koff];
#pragma unroll
        for (int nt = 0; nt < 8; nt++) {
            short8 bf = *(const short8*)&Wsw[((nt * 4 + ks) * 64 + lane) * 8];
            acc[nt] = __builtin_amdgcn_mfma_f32_16x16x32_bf16(af, bf, acc[nt], 0, 0, 0);
        }
    }
    int orow0 = row0 + wave * 16 + (lane >> 4) * 4;
    int ocol = lane & 15;
#pragma unroll
    for (int nt = 0; nt < 8; nt++) {
#pragma unroll
        for (int r = 0; r < 4; r++) {
            int row = orow0 + r;
            if (row < NN) H[(size_t)row * CH + nt * 16 + ocol] = f2bf(acc[nt][r]);
        }
    }
}

// ---------------- GCN aggregation: 4 edges/iter, 16-lane row slices, prefetch ----------------
__launch_bounds__(256)
__global__ void k_gcn_agg(const unsigned short* __restrict__ H, const int* __restrict__ csr,
                          const int* __restrict__ rowptr, const float* __restrict__ dinv,
                          const float* __restrict__ b1, unsigned short* __restrict__ T,
                          float* __restrict__ stats) {
    __shared__ float red_s[4][128], red_q[4][128];
    int t = threadIdx.x, wave = t >> 6, lane = t & 63;
    int g = lane >> 4, sl = lane & 15;
    float4 bb0 = *(const float4*)&b1[sl * 8];
    float4 bb1 = *(const float4*)&b1[sl * 8 + 4];
    float bias[8] = {bb0.x, bb0.y, bb0.z, bb0.w, bb1.x, bb1.y, bb1.z, bb1.w};
    float ssum[8], ssq[8];
#pragma unroll
    for (int j = 0; j < 8; j++) { ssum[j] = 0.f; ssq[j] = 0.f; }
    for (int node = blockIdx.x * 4 + wave; node < NN; node += gridDim.x * 4) {
        int beg = rowptr[node], end = rowptr[node + 1];
        float di = dinv[node];
        float acc[8];
#pragma unroll
        for (int j = 0; j < 8; j++) acc[j] = 0.f;
        int kk0 = beg + g;
        int s_cur = csr[kk0 < end ? kk0 : end - 1];
        for (int k = beg; k < end; k += 4) {
            int kn = k + 4 + g;
            int s_next = csr[kn < end ? kn : end - 1];
            bool valid = (k + g) < end;
            float w = valid ? dinv[s_cur] : 0.f;
            uint4 u = *(const uint4*)&H[(size_t)s_cur * CH + sl * 8];
            acc[0] = fmaf(w, bflo(u.x), acc[0]); acc[1] = fmaf(w, bfhi(u.x), acc[1]);
            acc[2] = fmaf(w, bflo(u.y), acc[2]); acc[3] = fmaf(w, bfhi(u.y), acc[3]);
            acc[4] = fmaf(w, bflo(u.z), acc[4]); acc[5] = fmaf(w, bfhi(u.z), acc[5]);
            acc[6] = fmaf(w, bflo(u.w), acc[6]); acc[7] = fmaf(w, bfhi(u.w), acc[7]);
            s_cur = s_next;
        }
#pragma unroll
        for (int j = 0; j < 8; j++) {
            acc[j] += __shfl_xor(acc[j], 16);
            acc[j] += __shfl_xor(acc[j], 32);
        }
        if (lane < 16) {
            short8 sv;
#pragma unroll
            for (int j = 0; j < 8; j++) {
                float tv = fmaf(di, acc[j], bias[j]);
                sv[j] = (short)f2bf(tv);
                ssum[j] += tv; ssq[j] = fmaf(tv, tv, ssq[j]);
            }
            *(short8*)&T[(size_t)node * CH + sl * 8] = sv;
        }
    }
    if (lane < 16) {
#pragma unroll
        for (int j = 0; j < 8; j++) { red_s[wave][sl * 8 + j] = ssum[j]; red_q[wave][sl * 8 + j] = ssq[j]; }
    }
    __syncthreads();
    if (t < 128) {
        float s = 0.f, q = 0.f;
        for (int w2 = 0; w2 < 4; w2++) { s += red_s[w2][t]; q += red_q[w2][t]; }
        float* bank = stats + (blockIdx.x & 7) * 256;
        atomicAdd(&bank[t], s);
        atomicAdd(&bank[128 + t], q);
    }
}

// ---------------- GraphNorm finalize ----------------
__global__ void k_fin(const float* __restrict__ stats, const float* __restrict__ gw,
                      const float* __restrict__ gb, const float* __restrict__ gms,
                      float* __restrict__ alpha, float* __restrict__ beta) {
    int c = threadIdx.x;  // 128 threads
    float s = 0.f, q = 0.f;
    for (int b = 0; b < 8; b++) { s += stats[b * 256 + c]; q += stats[b * 256 + 128 + c]; }
    float mean = s * (1.f / NN);
    float ctr = gms[c] * mean;
    float var = q * (1.f / NN) - 2.f * ctr * mean + ctr * ctr;
    float al = gw[c] * rsqrtf(var + EPSV);
    alpha[c] = al;
    beta[c] = gb[c] - al * ctr;
}

// ---------------- GEMM 2 (fused): x1 = x + lrelu(a1*T+b1); H=x1@Wg; a_s,a_d ----------------
__launch_bounds__(256, 4)
__global__ void k_gemm2(const float* __restrict__ X, const unsigned short* __restrict__ T,
                        const unsigned short* __restrict__ Wsw, const float* __restrict__ alpha,
                        const float* __restrict__ beta, const float* __restrict__ attS,
                        const float* __restrict__ attD, float* __restrict__ X1out,
                        unsigned short* __restrict__ H, float* __restrict__ a_s, float* __restrict__ a_d) {
    __shared__ __align__(16) short Xl[64 * 136];
    int t = threadIdx.x, wave = t >> 6, lane = t & 63;
    int row0 = blockIdx.x * 64;
    {   // fused staging: x1 = x + lrelu(alpha*T+beta); store fp32 X1out; bf16 -> LDS
        int r = t >> 2, q = t & 3;
        int gr = row0 + r;
        size_t base = (size_t)gr * CH;
#pragma unroll
        for (int j = 0; j < 4; j++) {
            int c0 = q * 32 + j * 8;
            float4 v0 = {0.f,0.f,0.f,0.f}, v1 = {0.f,0.f,0.f,0.f};
            if (gr < NN) {
                float4 xv0 = *(const float4*)&X[base + c0];
                float4 xv1 = *(const float4*)&X[base + c0 + 4];
                uint4 tu = *(const uint4*)&T[base + c0];
                float4 al0 = *(const float4*)&alpha[c0];
                float4 al1 = *(const float4*)&alpha[c0 + 4];
                float4 be0 = *(const float4*)&beta[c0];
                float4 be1 = *(const float4*)&beta[c0 + 4];
                v0.x = xv0.x + lrelu(fmaf(al0.x, bflo(tu.x), be0.x), 0.01f);
                v0.y = xv0.y + lrelu(fmaf(al0.y, bfhi(tu.x), be0.y), 0.01f);
                v0.z = xv0.z + lrelu(fmaf(al0.z, bflo(tu.y), be0.z), 0.01f);
                v0.w = xv0.w + lrelu(fmaf(al0.w, bfhi(tu.y), be0.w), 0.01f);
                v1.x = xv1.x + lrelu(fmaf(al1.x, bflo(tu.z), be1.x), 0.01f);
                v1.y = xv1.y + lrelu(fmaf(al1.y, bfhi(tu.z), be1.y), 0.01f);
                v1.z = xv1.z + lrelu(fmaf(al1.z, bflo(tu.w), be1.z), 0.01f);
                v1.w = xv1.w + lrelu(fmaf(al1.w, bfhi(tu.w), be1.w), 0.01f);
                *(float4*)&X1out[base + c0] = v0;
                *(float4*)&X1out[base + c0 + 4] = v1;
            }
            short8 s;
            s[0]=f2bf(v0.x); s[1]=f2bf(v0.y); s[2]=f2bf(v0.z); s[3]=f2bf(v0.w);
            s[4]=f2bf(v1.x); s[5]=f2bf(v1.y); s[6]=f2bf(v1.z); s[7]=f2bf(v1.w);
            *(short8*)&Xl[r * 136 + c0] = s;
        }
    }
    __syncthreads();
    floatx4 acc[8];
#pragma unroll
    for (int nt = 0; nt < 8; nt++) acc[nt] = (floatx4){0.f, 0.f, 0.f, 0.f};
    int arow = wave * 16 + (lane & 15);
    int koff = (lane >> 4) * 8;
#pragma unroll
    for (int ks = 0; ks < 4; ks++) {
        short8 af = *(short8*)&Xl[arow * 136 + ks * 32 + koff];
#pragma unroll
        for (int nt = 0; nt < 8; nt++) {
            short8 bf = *(const short8*)&Wsw[((nt * 4 + ks) * 64 + lane) * 8];
            acc[nt] = __builtin_amdgcn_mfma_f32_16x16x32_bf16(af, bf, acc[nt], 0, 0, 0);
        }
    }
    int orow0 = row0 + wave * 16 + (lane >> 4) * 4;
    int ocol = lane & 15;
    float ps[4] = {0.f, 0.f, 0.f, 0.f}, pd[4] = {0.f, 0.f, 0.f, 0.f};
#pragma unroll
    for (int nt = 0; nt < 8; nt++) {
        float as_v = attS[nt * 16 + ocol];
        float ad_v = attD[nt * 16 + ocol];
#pragma unroll
        for (int r = 0; r < 4; r++) {
            int row = orow0 + r;
            if (row < NN) H[(size_t)row * CH + nt * 16 + ocol] = f2bf(acc[nt][r]);
            ps[r] = fmaf(acc[nt][r], as_v, ps[r]);
            pd[r] = fmaf(acc[nt][r], ad_v, pd[r]);
        }
    }
#pragma unroll
    for (int off = 1; off < 16; off <<= 1) {
#pragma unroll
        for (int r = 0; r < 4; r++) {
            ps[r] += __shfl_xor(ps[r], off);
            pd[r] += __shfl_xor(pd[r], off);
        }
    }
    if ((lane & 15) == 0) {
#pragma unroll
        for (int r = 0; r < 4; r++) {
            int row = orow0 + r;
            if (row < NN) { a_s[row] = ps[r]; a_d[row] = pd[r]; }
        }
    }
}

// ---------------- GAT aggregation: single-pass softmax (no max needed; |e|<~10) ----------------
__launch_bounds__(256)
__global__ void k_gat_agg(const unsigned short* __restrict__ H, const int* __restrict__ csr,
                          const int* __restrict__ rowptr, const float* __restrict__ a_s,
                          const float* __restrict__ a_d, const float* __restrict__ bg,
                          unsigned short* __restrict__ T, float* __restrict__ stats) {
    __shared__ float red_s[4][128], red_q[4][128];
    int t = threadIdx.x, wave = t >> 6, lane = t & 63;
    int g = lane >> 4, sl = lane & 15;
    float4 bb0 = *(const float4*)&bg[sl * 8];
    float4 bb1 = *(const float4*)&bg[sl * 8 + 4];
    float bias[8] = {bb0.x, bb0.y, bb0.z, bb0.w, bb1.x, bb1.y, bb1.z, bb1.w};
    float ssum[8], ssq[8];
#pragma unroll
    for (int j = 0; j < 8; j++) { ssum[j] = 0.f; ssq[j] = 0.f; }
    for (int node = blockIdx.x * 4 + wave; node < NN; node += gridDim.x * 4) {
        int beg = rowptr[node], end = rowptr[node + 1];
        float adI = a_d[node];
        float acc[8];
#pragma unroll
        for (int j = 0; j < 8; j++) acc[j] = 0.f;
        float den = 0.f;
        int kk0 = beg + g;
        int s_cur = csr[kk0 < end ? kk0 : end - 1];
        for (int k = beg; k < end; k += 4) {
            int kn = k + 4 + g;
            int s_next = csr[kn < end ? kn : end - 1];
            bool valid = (k + g) < end;
            float e = lrelu(a_s[s_cur] + adI, 0.2f);
            float wgt = valid ? __expf(e) : 0.f;
            den += wgt;
            uint4 u = *(const uint4*)&H[(size_t)s_cur * CH + sl * 8];
            acc[0] = fmaf(wgt, bflo(u.x), acc[0]); acc[1] = fmaf(wgt, bfhi(u.x), acc[1]);
            acc[2] = fmaf(wgt, bflo(u.y), acc[2]); acc[3] = fmaf(wgt, bfhi(u.y), acc[3]);
            acc[4] = fmaf(wgt, bflo(u.z), acc[4]); acc[5] = fmaf(wgt, bfhi(u.z), acc[5]);
            acc[6] = fmaf(wgt, bflo(u.w), acc[6]); acc[7] = fmaf(wgt, bfhi(u.w), acc[7]);
            s_cur = s_next;
        }
#pragma unroll
        for (int j = 0; j < 8; j++) {
            acc[j] += __shfl_xor(acc[j], 16);
            acc[j] += __shfl_xor(acc[j], 32);
        }
        den += __shfl_xor(den, 16);
        den += __shfl_xor(den, 32);
        float inv = 1.f / den;
        if (lane < 16) {
            short8 sv;
#pragma unroll
            for (int j = 0; j < 8; j++) {
                float tv = fmaf(acc[j], inv, bias[j]);
                sv[j] = (short)f2bf(tv);
                ssum[j] += tv; ssq[j] = fmaf(tv, tv, ssq[j]);
            }
            *(short8*)&T[(size_t)node * CH + sl * 8] = sv;
        }
    }
    if (lane < 16) {
#pragma unroll
        for (int j = 0; j < 8; j++) { red_s[wave][sl * 8 + j] = ssum[j]; red_q[wave][sl * 8 + j] = ssq[j]; }
    }
    __syncthreads();
    if (t < 128) {
        float s = 0.f, q = 0.f;
        for (int w2 = 0; w2 < 4; w2++) { s += red_s[w2][t]; q += red_q[w2][t]; }
        float* bank = stats + (blockIdx.x & 7) * 256;
        atomicAdd(&bank[t], s);
        atomicAdd(&bank[128 + t], q);
    }
}

// ---------------- final: out = x1 + lrelu(a2*T2+b2)  (T2 bf16) ----------------
__global__ void k_final(const unsigned short* __restrict__ T, const float* __restrict__ alpha,
                        const float* __restrict__ beta, float* __restrict__ out) {
    size_t i = (size_t)(blockIdx.x * 256 + threadIdx.x) * 4;
    if (i >= (size_t)NN * CH) return;
    int c = (int)(i & (CH - 1));
    uint2 tu = *(const uint2*)&T[i];
    float4 av = *(const float4*)&alpha[c];
    float4 bv = *(const float4*)&beta[c];
    float4 o = *(float4*)&out[i];
    o.x += lrelu(fmaf(av.x, bflo(tu.x), bv.x), 0.01f);
    o.y += lrelu(fmaf(av.y, bfhi(tu.x), bv.y), 0.01f);
    o.z += lrelu(fmaf(av.z, bflo(tu.y), bv.z), 0.01f);
    o.w += lrelu(fmaf(av.w, bfhi(tu.y), bv.w), 0.01f);
    *(float4*)&out[i] = o;
}

extern "C" void kernel_launch(void* const* d_in, const int* in_sizes, int n_in,
                              void* d_out, int out_size, void* d_ws, size_t ws_size,
                              hipStream_t stream) {
    const float* x    = (const float*)d_in[0];
    const int*   edges= (const int*)d_in[1];
    const float* W1   = (const float*)d_in[2];
    const float* b1   = (const float*)d_in[3];
    const float* gw   = (const float*)d_in[4];
    const float* gb   = (const float*)d_in[5];
    const float* gms  = (const float*)d_in[6];
    const float* Wg   = (const float*)d_in[7];
    const float* bg   = (const float*)d_in[8];
    const float* attS = (const float*)d_in[9];
    const float* attD = (const float*)d_in[10];
    float* out = (float*)d_out;

    char* w = (char*)d_ws;
    size_t o = 0;
    unsigned short* H = (unsigned short*)(w + o); o += (size_t)NN * CH * 2;  // 25.6 MB bf16
    unsigned short* T = (unsigned short*)(w + o); o += (size_t)NN * CH * 2;  // 25.6 MB bf16
    int*   csr    = (int*)(w + o);   o += (size_t)TOTE * 4;                  // 6.8 MB
    int*   rowptr = (int*)(w + o);   o += (size_t)(NN + 64) * 4;
    int*   deg    = (int*)(w + o);   o += (size_t)NN * 4;
    int*   cursor = (int*)(w + o);   o += (size_t)NN * 4;
    float* dinv   = (float*)(w + o); o += (size_t)NN * 4;
    float* a_s    = (float*)(w + o); o += (size_t)NN * 4;
    float* a_d    = (float*)(w + o); o += (size_t)NN * 4;
    int*   bsum   = (int*)(w + o);   o += 512;
    int*   boff   = (int*)(w + o);   o += 512;
    float* stats  = (float*)(w + o); o += 4096 * 4;
    float* alpha1 = (float*)(w + o); o += 512;
    float* beta1  = (float*)(w + o); o += 512;
    float* alpha2 = (float*)(w + o); o += 512;
    float* beta2  = (float*)(w + o); o += 512;
    unsigned short* Wsw1 = (unsigned short*)(w + o); o += 16384 * 2;
    unsigned short* Wsw2 = (unsigned short*)(w + o); o += 16384 * 2;

    k_init <<<(NN + 255) / 256, 256, 0, stream>>>(deg, cursor, stats);
    k_count<<<(NE + 255) / 256, 256, 0, stream>>>(edges, deg);
    k_scan1<<<NB, 256, 0, stream>>>(deg, bsum, dinv);
    k_scan2<<<1, 32, 0, stream>>>(bsum, boff);
    k_scan3<<<NB, 256, 0, stream>>>(deg, boff, rowptr);
    k_fill <<<(TOTE + 255) / 256, 256, 0, stream>>>(edges, rowptr, cursor, csr, 0, NN / 2);
    k_fill <<<(TOTE + 255) / 256, 256, 0, stream>>>(edges, rowptr, cursor, csr, NN / 2, NN);
    k_wswz <<<64, 256, 0, stream>>>(W1, Wg, Wsw1, Wsw2);

    k_gemm1  <<<NGB, 256, 0, stream>>>(x, Wsw1, H);
    k_gcn_agg<<<2048, 256, 0, stream>>>(H, csr, rowptr, dinv, b1, T, stats);
    k_fin    <<<1, 128, 0, stream>>>(stats, gw, gb, gms, alpha1, beta1);

    k_gemm2  <<<NGB, 256, 0, stream>>>(x, T, Wsw2, alpha1, beta1, attS, attD, out, H, a_s, a_d);
    k_gat_agg<<<2048, 256, 0, stream>>>(H, csr, rowptr, a_s, a_d, bg, T, stats + 2048);
    k_fin    <<<1, 128, 0, stream>>>(stats + 2048, gw, gb, gms, alpha2, beta2);

    k_final<<<(NN * CH / 4 + 255) / 256, 256, 0, stream>>>(T, alpha2, beta2, out);
}